// Round 1
// baseline (4826.376 us; speedup 1.0000x reference)
//
#include <hip/hip_runtime.h>
#include <math.h>

#define S_LEN 2048
#define DMODEL 512
#define NHEADS 8
#define HDIM 64
#define EPS_G 1e-8f

// ---------------------------------------------------------------------------
// Kernel 1: fused QKV projection.  out[i,j] = sum_k X[i,k]*W[j,k] + b[j]
// X: (4096, 512) row-major. W: (512,512) row-major (we need W^T GEMM => dot of
// rows, both contiguous along k).  BM=64, BN=64, BK=32, 256 threads, 4x4/thread.
// Store head-split: buf[(n*8+h)*2048 + s][dh]   (one 64-col block == one head)
// ---------------------------------------------------------------------------
__global__ __launch_bounds__(256) void qkv_gemm(
    const float* __restrict__ X,
    const float* __restrict__ Wq, const float* __restrict__ Wk, const float* __restrict__ Wv,
    const float* __restrict__ bq, const float* __restrict__ bk, const float* __restrict__ bv,
    float* __restrict__ Qb, float* __restrict__ Kb, float* __restrict__ Vb) {
  const int i0 = blockIdx.x << 6;      // row tile (0..4095 step 64), within one n
  const int jb = blockIdx.y;           // 0..23 : which (0..2) x head (0..7)
  const int which = jb >> 3;
  const int h = jb & 7;
  const float* __restrict__ W    = (which == 0) ? Wq : (which == 1) ? Wk : Wv;
  const float* __restrict__ bias = (which == 0) ? bq : (which == 1) ? bk : bv;
  float* __restrict__ Ob         = (which == 0) ? Qb : (which == 1) ? Kb : Vb;
  const int j0 = h << 6;               // column offset inside the 512-wide W

  __shared__ float Xs[32][68];         // [k][m], padded
  __shared__ float Ws[32][68];         // [k][n], padded
  const int tid = threadIdx.x;
  const int tx = tid & 15, ty = tid >> 4;

  float acc[4][4];
#pragma unroll
  for (int i = 0; i < 4; ++i)
#pragma unroll
    for (int j = 0; j < 4; ++j) acc[i][j] = 0.f;

  for (int k0 = 0; k0 < 512; k0 += 32) {
    __syncthreads();
#pragma unroll
    for (int pass = 0; pass < 2; ++pass) {
      int idx = tid + (pass << 8);         // 0..511 : 64 rows x 8 float4
      int r = idx >> 3, c4 = (idx & 7) << 2;
      float4 x4 = *(const float4*)(X + (size_t)(i0 + r) * 512 + k0 + c4);
      Xs[c4 + 0][r] = x4.x; Xs[c4 + 1][r] = x4.y; Xs[c4 + 2][r] = x4.z; Xs[c4 + 3][r] = x4.w;
      float4 w4 = *(const float4*)(W + (size_t)(j0 + r) * 512 + k0 + c4);
      Ws[c4 + 0][r] = w4.x; Ws[c4 + 1][r] = w4.y; Ws[c4 + 2][r] = w4.z; Ws[c4 + 3][r] = w4.w;
    }
    __syncthreads();
#pragma unroll
    for (int k = 0; k < 32; ++k) {
      float4 a4 = *(const float4*)(&Xs[k][ty << 2]);
      float4 b4 = *(const float4*)(&Ws[k][tx << 2]);
      float ar[4] = {a4.x, a4.y, a4.z, a4.w};
      float br[4] = {b4.x, b4.y, b4.z, b4.w};
#pragma unroll
      for (int ii = 0; ii < 4; ++ii)
#pragma unroll
        for (int jj = 0; jj < 4; ++jj) acc[ii][jj] += ar[ii] * br[jj];
    }
  }

  const int n = i0 >> 11;
  const int sb = i0 & 2047;
  const int nh = (n << 3) + h;
  const float b0 = bias[j0 + (tx << 2) + 0];
  const float b1 = bias[j0 + (tx << 2) + 1];
  const float b2 = bias[j0 + (tx << 2) + 2];
  const float b3 = bias[j0 + (tx << 2) + 3];
#pragma unroll
  for (int ii = 0; ii < 4; ++ii) {
    int srow = sb + (ty << 2) + ii;
    float4 o;
    o.x = acc[ii][0] + b0; o.y = acc[ii][1] + b1;
    o.z = acc[ii][2] + b2; o.w = acc[ii][3] + b3;
    *(float4*)(Ob + ((size_t)nh * S_LEN + srow) * HDIM + (tx << 2)) = o;
  }
}

// ---------------------------------------------------------------------------
// Kernel 2: xPos rotary + scale, in place on Qb/Kb.  Q also gets *0.125
// (reference scales Q before xpos; xpos is linear so it commutes).
// One thread per (nh, s, dim-pair k in 0..31).
// ---------------------------------------------------------------------------
__global__ __launch_bounds__(256) void xpos_kernel(float* __restrict__ Qb,
                                                   float* __restrict__ Kb,
                                                   const int* __restrict__ pos) {
  int id = blockIdx.x * 256 + threadIdx.x;   // 16*2048*32 = 1,048,576 exactly
  int k  = id & 31;
  int s  = (id >> 5) & 2047;
  int nh = id >> 16;
  int n  = nh >> 3;

  float p = (float)pos[n * S_LEN + s];
  float half = 2.0f * (float)k;
  // inv_freq = 10000^(-half/64) = 2^(-k * log2(10000)/32)
  float inv_freq = exp2f(-0.41524100f * (float)k);
  float ang = p * inv_freq;
  float sn = sinf(ang), cn = cosf(ang);
  float sv = (half + 25.6f) * (1.0f / 89.6f);
  float e  = p * (1.0f / 512.0f) * log2f(sv);
  float sclQ = exp2f(e) * 0.125f;     // downscale=False, fused * HEAD_DIM^-0.5
  float sclK = exp2f(-e);             // downscale=True

  size_t base = ((size_t)nh * S_LEN + s) * HDIM + 2 * k;
  float2 q = *(float2*)(Qb + base);
  float2 kk = *(float2*)(Kb + base);
  float2 qo, ko;
  qo.x = (q.x * cn - q.y * sn) * sclQ;
  qo.y = (q.y * cn + q.x * sn) * sclQ;
  ko.x = (kk.x * cn - kk.y * sn) * sclK;
  ko.y = (kk.y * cn + kk.x * sn) * sclK;
  *(float2*)(Qb + base) = qo;
  *(float2*)(Kb + base) = ko;
}

// ---------------------------------------------------------------------------
// Kernel 3: fused sigmoid-gated attention with right-to-left suffix scan.
// Grid: 16 heads x 32 row-blocks.  512 threads = 8 waves; wave owns 8 rows.
// Per 64-key tile: logits (lane=key), per-row 64-lane suffix-product scan,
// PV update (lane=dim) with K/V LDS reads shared across 4-row groups.
// Gate identity: A_fin[t] = a[t]*P[t-1], P[t]=prod_{w>=t} f[w], f=1-a+eps;
// column-0 boundary handled by a pending rank-1 term resolved next tile.
// ---------------------------------------------------------------------------
__global__ __launch_bounds__(512) void attn_kernel(const float* __restrict__ Qb,
                                                   const float* __restrict__ Kb,
                                                   const float* __restrict__ Vb,
                                                   const float* __restrict__ imask,
                                                   float* __restrict__ att) {
  const int id = blockIdx.x;
  const int nh = id >> 5;
  const int rbi = id & 31;
  const int rb = (id < 256) ? rbi : (31 - rbi);   // pair heavy+light across CUs
  const int n = nh >> 3;
  const int h = nh & 7;
  const int tid = threadIdx.x;
  const int wave = tid >> 6;
  const int lane = tid & 63;

  __shared__ float Qs[64][64];      // broadcast-only reads -> no pad needed
  __shared__ float Ks[64][68];
  __shared__ float Vs[64][68];
  __shared__ float cs[8][4][64];    // per-wave coefficient rows (4-row group)
  __shared__ float msk[64];

  const size_t headoff = (size_t)nh * S_LEN * HDIM;

  // stage this block's 64 Q rows once
  for (int idx = tid; idx < 64 * 16; idx += 512) {
    int r = idx >> 4, c4 = (idx & 15) << 2;
    *(float4*)(&Qs[r][c4]) =
        *(const float4*)(Qb + headoff + (size_t)(rb * 64 + r) * HDIM + c4);
  }

  float outv[8], pend[8], Crow[8];
#pragma unroll
  for (int i = 0; i < 8; ++i) { outv[i] = 0.f; pend[i] = 0.f; Crow[i] = 1.f; }

  for (int jt = rb; jt >= 0; --jt) {
    __syncthreads();
    for (int idx = tid; idx < 64 * 16; idx += 512) {
      int r = idx >> 4, c4 = (idx & 15) << 2;
      *(float4*)(&Ks[r][c4]) =
          *(const float4*)(Kb + headoff + (size_t)(jt * 64 + r) * HDIM + c4);
      *(float4*)(&Vs[r][c4]) =
          *(const float4*)(Vb + headoff + (size_t)(jt * 64 + r) * HDIM + c4);
    }
    if (tid < 64) msk[tid] = imask[n * S_LEN + jt * 64 + tid];
    __syncthreads();

    const int tkey = jt * 64 + lane;
    const float mv = msk[lane];
    const float v0 = Vs[0][lane];

#pragma unroll
    for (int rg = 0; rg < 2; ++rg) {
      // ---- logits for 4 rows (lane = key) ----
      float acc[4];
#pragma unroll
      for (int rr = 0; rr < 4; ++rr) acc[rr] = 0.f;
#pragma unroll
      for (int d4 = 0; d4 < 16; ++d4) {
        const float4 k4 = *(const float4*)(&Ks[lane][d4 << 2]);
#pragma unroll
        for (int rr = 0; rr < 4; ++rr) {
          const float4 q4 =
              *(const float4*)(&Qs[(wave << 3) + (rg << 2) + rr][d4 << 2]);
          acc[rr] += k4.x * q4.x + k4.y * q4.y + k4.z * q4.z + k4.w * q4.w;
        }
      }

      float f63v[4], s0v[4];
#pragma unroll
      for (int rr = 0; rr < 4; ++rr) {
        const int ri = (rg << 2) + rr;
        const int srow = rb * 64 + (wave << 3) + ri;
        float a = (tkey <= srow) ? (mv / (1.0f + expf(-acc[rr]))) : 0.0f;
        float f = 1.0f - a + EPS_G;
        // inclusive suffix product over 64 lanes: p[l] = prod_{w>=l} f[w]
        float p = f;
#pragma unroll
        for (int off = 1; off < 64; off <<= 1) {
          float v = __shfl_down(p, off);
          p *= (lane + off < 64) ? v : 1.0f;
        }
        float qprev = __shfl_up(p, 1);  // lane l gets p[l-1]; lane 0 unused
        float c = (lane == 0) ? ((jt == 0) ? a : 0.0f)
                              : (a * qprev * Crow[ri]);
        cs[wave][rr][lane] = c;
        float ptile = __shfl(p, 0);     // full tile product
        float a0    = __shfl(a, 0);
        f63v[rr] = __shfl(f, 63);
        s0v[rr]  = a0 * ptile * Crow[ri];   // pending coeff for column t0
        Crow[ri] *= ptile;
      }

      // ---- PV update (lane = dim) ----
#pragma unroll
      for (int rr = 0; rr < 4; ++rr)
        outv[(rg << 2) + rr] += pend[(rg << 2) + rr] * f63v[rr]; // resolve old
#pragma unroll
      for (int l4 = 0; l4 < 16; ++l4) {
        const float vv0 = Vs[(l4 << 2) + 0][lane];
        const float vv1 = Vs[(l4 << 2) + 1][lane];
        const float vv2 = Vs[(l4 << 2) + 2][lane];
        const float vv3 = Vs[(l4 << 2) + 3][lane];
#pragma unroll
        for (int rr = 0; rr < 4; ++rr) {
          const float4 c4 = *(const float4*)(&cs[wave][rr][l4 << 2]);
          outv[(rg << 2) + rr] += c4.x * vv0 + c4.y * vv1 + c4.z * vv2 + c4.w * vv3;
        }
      }
#pragma unroll
      for (int rr = 0; rr < 4; ++rr)
        pend[(rg << 2) + rr] = s0v[rr] * v0;   // new pending (column t0)
    }
  }

  // store attended in (n, s, h*64+d) layout for the output GEMM
#pragma unroll
  for (int rr = 0; rr < 8; ++rr) {
    const int srow = rb * 64 + (wave << 3) + rr;
    att[(size_t)(n * S_LEN + srow) * DMODEL + h * HDIM + lane] = outv[rr];
  }
}

// ---------------------------------------------------------------------------
// Kernel 4: out = att @ Wo^T + bo   (same tiling as kernel 1, plain store)
// ---------------------------------------------------------------------------
__global__ __launch_bounds__(256) void out_gemm(const float* __restrict__ Xa,
                                                const float* __restrict__ Wo,
                                                const float* __restrict__ bo,
                                                float* __restrict__ Out) {
  const int i0 = blockIdx.x << 6;
  const int j0 = blockIdx.y << 6;

  __shared__ float Xs[32][68];
  __shared__ float Ws[32][68];
  const int tid = threadIdx.x;
  const int tx = tid & 15, ty = tid >> 4;

  float acc[4][4];
#pragma unroll
  for (int i = 0; i < 4; ++i)
#pragma unroll
    for (int j = 0; j < 4; ++j) acc[i][j] = 0.f;

  for (int k0 = 0; k0 < 512; k0 += 32) {
    __syncthreads();
#pragma unroll
    for (int pass = 0; pass < 2; ++pass) {
      int idx = tid + (pass << 8);
      int r = idx >> 3, c4 = (idx & 7) << 2;
      float4 x4 = *(const float4*)(Xa + (size_t)(i0 + r) * 512 + k0 + c4);
      Xs[c4 + 0][r] = x4.x; Xs[c4 + 1][r] = x4.y; Xs[c4 + 2][r] = x4.z; Xs[c4 + 3][r] = x4.w;
      float4 w4 = *(const float4*)(Wo + (size_t)(j0 + r) * 512 + k0 + c4);
      Ws[c4 + 0][r] = w4.x; Ws[c4 + 1][r] = w4.y; Ws[c4 + 2][r] = w4.z; Ws[c4 + 3][r] = w4.w;
    }
    __syncthreads();
#pragma unroll
    for (int k = 0; k < 32; ++k) {
      float4 a4 = *(const float4*)(&Xs[k][ty << 2]);
      float4 b4 = *(const float4*)(&Ws[k][tx << 2]);
      float ar[4] = {a4.x, a4.y, a4.z, a4.w};
      float br[4] = {b4.x, b4.y, b4.z, b4.w};
#pragma unroll
      for (int ii = 0; ii < 4; ++ii)
#pragma unroll
        for (int jj = 0; jj < 4; ++jj) acc[ii][jj] += ar[ii] * br[jj];
    }
  }

  const float b0 = bo[j0 + (tx << 2) + 0];
  const float b1 = bo[j0 + (tx << 2) + 1];
  const float b2 = bo[j0 + (tx << 2) + 2];
  const float b3 = bo[j0 + (tx << 2) + 3];
#pragma unroll
  for (int ii = 0; ii < 4; ++ii) {
    float4 o;
    o.x = acc[ii][0] + b0; o.y = acc[ii][1] + b1;
    o.z = acc[ii][2] + b2; o.w = acc[ii][3] + b3;
    *(float4*)(Out + (size_t)(i0 + (ty << 2) + ii) * 512 + j0 + (tx << 2)) = o;
  }
}

// ---------------------------------------------------------------------------
extern "C" void kernel_launch(void* const* d_in, const int* in_sizes, int n_in,
                              void* d_out, int out_size, void* d_ws, size_t ws_size,
                              hipStream_t stream) {
  (void)in_sizes; (void)n_in; (void)out_size; (void)ws_size;
  const float* seq  = (const float*)d_in[0];
  const float* mask = (const float*)d_in[1];
  const int*   pos  = (const int*)d_in[2];
  // d_in[3] = layer_num (unused by the reference math)
  const float* Wq = (const float*)d_in[4];
  const float* bq = (const float*)d_in[5];
  const float* Wk = (const float*)d_in[6];
  const float* bk = (const float*)d_in[7];
  const float* Wv = (const float*)d_in[8];
  const float* bv = (const float*)d_in[9];
  const float* Wo = (const float*)d_in[10];
  const float* bo = (const float*)d_in[11];
  float* out = (float*)d_out;

  float* ws = (float*)d_ws;
  const size_t HE = (size_t)16 * S_LEN * HDIM;   // 2,097,152 floats = 8 MB
  float* Qb  = ws;
  float* Kb  = Qb + HE;
  float* Vb  = Kb + HE;
  float* att = Vb + HE;                          // (4096, 512)

  qkv_gemm<<<dim3(64, 24), 256, 0, stream>>>(seq, Wq, Wk, Wv, bq, bk, bv, Qb, Kb, Vb);
  xpos_kernel<<<4096, 256, 0, stream>>>(Qb, Kb, pos);
  attn_kernel<<<512, 512, 0, stream>>>(Qb, Kb, Vb, mask, att);
  out_gemm<<<dim3(64, 8), 256, 0, stream>>>(att, Wo, bo, out);
}

// Round 2
// 568.890 us; speedup vs baseline: 8.4838x; 8.4838x over previous
//
#include <hip/hip_runtime.h>
#include <math.h>

#define S_LEN 2048
#define DMODEL 512
#define NHEADS 8
#define HDIM 64
#define EPS_G 1e-8f

// ---------------------------------------------------------------------------
// Kernel 1: fused QKV projection.  out[i,j] = sum_k X[i,k]*W[j,k] + b[j]
// BM=64, BN=64, BK=32, 256 threads, 4x4/thread.
// Store head-split: buf[(n*8+h)*2048 + s][dh]
// ---------------------------------------------------------------------------
__global__ __launch_bounds__(256) void qkv_gemm(
    const float* __restrict__ X,
    const float* __restrict__ Wq, const float* __restrict__ Wk, const float* __restrict__ Wv,
    const float* __restrict__ bq, const float* __restrict__ bk, const float* __restrict__ bv,
    float* __restrict__ Qb, float* __restrict__ Kb, float* __restrict__ Vb) {
  const int i0 = blockIdx.x << 6;
  const int jb = blockIdx.y;
  const int which = jb >> 3;
  const int h = jb & 7;
  const float* __restrict__ W    = (which == 0) ? Wq : (which == 1) ? Wk : Wv;
  const float* __restrict__ bias = (which == 0) ? bq : (which == 1) ? bk : bv;
  float* __restrict__ Ob         = (which == 0) ? Qb : (which == 1) ? Kb : Vb;
  const int j0 = h << 6;

  __shared__ float Xs[32][68];
  __shared__ float Ws[32][68];
  const int tid = threadIdx.x;
  const int tx = tid & 15, ty = tid >> 4;

  float acc[4][4];
#pragma unroll
  for (int i = 0; i < 4; ++i)
#pragma unroll
    for (int j = 0; j < 4; ++j) acc[i][j] = 0.f;

  for (int k0 = 0; k0 < 512; k0 += 32) {
    __syncthreads();
#pragma unroll
    for (int pass = 0; pass < 2; ++pass) {
      int idx = tid + (pass << 8);
      int r = idx >> 3, c4 = (idx & 7) << 2;
      float4 x4 = *(const float4*)(X + (size_t)(i0 + r) * 512 + k0 + c4);
      Xs[c4 + 0][r] = x4.x; Xs[c4 + 1][r] = x4.y; Xs[c4 + 2][r] = x4.z; Xs[c4 + 3][r] = x4.w;
      float4 w4 = *(const float4*)(W + (size_t)(j0 + r) * 512 + k0 + c4);
      Ws[c4 + 0][r] = w4.x; Ws[c4 + 1][r] = w4.y; Ws[c4 + 2][r] = w4.z; Ws[c4 + 3][r] = w4.w;
    }
    __syncthreads();
#pragma unroll
    for (int k = 0; k < 32; ++k) {
      float4 a4 = *(const float4*)(&Xs[k][ty << 2]);
      float4 b4 = *(const float4*)(&Ws[k][tx << 2]);
      float ar[4] = {a4.x, a4.y, a4.z, a4.w};
      float br[4] = {b4.x, b4.y, b4.z, b4.w};
#pragma unroll
      for (int ii = 0; ii < 4; ++ii)
#pragma unroll
        for (int jj = 0; jj < 4; ++jj) acc[ii][jj] += ar[ii] * br[jj];
    }
  }

  const int n = i0 >> 11;
  const int sb = i0 & 2047;
  const int nh = (n << 3) + h;
  const float b0 = bias[j0 + (tx << 2) + 0];
  const float b1 = bias[j0 + (tx << 2) + 1];
  const float b2 = bias[j0 + (tx << 2) + 2];
  const float b3 = bias[j0 + (tx << 2) + 3];
#pragma unroll
  for (int ii = 0; ii < 4; ++ii) {
    int srow = sb + (ty << 2) + ii;
    float4 o;
    o.x = acc[ii][0] + b0; o.y = acc[ii][1] + b1;
    o.z = acc[ii][2] + b2; o.w = acc[ii][3] + b3;
    *(float4*)(Ob + ((size_t)nh * S_LEN + srow) * HDIM + (tx << 2)) = o;
  }
}

// ---------------------------------------------------------------------------
// Kernel 2: xPos rotary + scale, in place on Qb/Kb.
// ---------------------------------------------------------------------------
__global__ __launch_bounds__(256) void xpos_kernel(float* __restrict__ Qb,
                                                   float* __restrict__ Kb,
                                                   const int* __restrict__ pos) {
  int id = blockIdx.x * 256 + threadIdx.x;
  int k  = id & 31;
  int s  = (id >> 5) & 2047;
  int nh = id >> 16;
  int n  = nh >> 3;

  float p = (float)pos[n * S_LEN + s];
  float half = 2.0f * (float)k;
  float inv_freq = exp2f(-0.41524100f * (float)k);
  float ang = p * inv_freq;
  float sn = sinf(ang), cn = cosf(ang);
  float sv = (half + 25.6f) * (1.0f / 89.6f);
  float e  = p * (1.0f / 512.0f) * log2f(sv);
  float sclQ = exp2f(e) * 0.125f;
  float sclK = exp2f(-e);

  size_t base = ((size_t)nh * S_LEN + s) * HDIM + 2 * k;
  float2 q = *(float2*)(Qb + base);
  float2 kk = *(float2*)(Kb + base);
  float2 qo, ko;
  qo.x = (q.x * cn - q.y * sn) * sclQ;
  qo.y = (q.y * cn + q.x * sn) * sclQ;
  ko.x = (kk.x * cn - kk.y * sn) * sclK;
  ko.y = (kk.y * cn + kk.x * sn) * sclK;
  *(float2*)(Qb + base) = qo;
  *(float2*)(Kb + base) = ko;
}

// ---------------------------------------------------------------------------
// Kernel 3: fused sigmoid-gated attention with right-to-left suffix scan.
// R2 changes: __launch_bounds__(512,2) (256-VGPR budget — R1 spilled ~11.8 GB
// of scratch traffic at the compiler's 128-VGPR occupancy heuristic), and
// partial unrolls (2-deep) on the two inner loops so the hoisted LDS-load
// live set stays ~40-50 VGPRs instead of 80-256.
// ---------------------------------------------------------------------------
__global__ __launch_bounds__(512, 2) void attn_kernel(const float* __restrict__ Qb,
                                                      const float* __restrict__ Kb,
                                                      const float* __restrict__ Vb,
                                                      const float* __restrict__ imask,
                                                      float* __restrict__ att) {
  const int id = blockIdx.x;
  const int nh = id >> 5;
  const int rbi = id & 31;
  const int rb = (id < 256) ? rbi : (31 - rbi);   // pair heavy+light across CUs
  const int n = nh >> 3;
  const int h = nh & 7;
  const int tid = threadIdx.x;
  const int wave = tid >> 6;
  const int lane = tid & 63;

  __shared__ float Qs[64][64];
  __shared__ float Ks[64][68];
  __shared__ float Vs[64][68];
  __shared__ float cs[8][4][64];
  __shared__ float msk[64];

  const size_t headoff = (size_t)nh * S_LEN * HDIM;

  for (int idx = tid; idx < 64 * 16; idx += 512) {
    int r = idx >> 4, c4 = (idx & 15) << 2;
    *(float4*)(&Qs[r][c4]) =
        *(const float4*)(Qb + headoff + (size_t)(rb * 64 + r) * HDIM + c4);
  }

  float outv[8], pend[8], Crow[8];
#pragma unroll
  for (int i = 0; i < 8; ++i) { outv[i] = 0.f; pend[i] = 0.f; Crow[i] = 1.f; }

  for (int jt = rb; jt >= 0; --jt) {
    __syncthreads();
    for (int idx = tid; idx < 64 * 16; idx += 512) {
      int r = idx >> 4, c4 = (idx & 15) << 2;
      *(float4*)(&Ks[r][c4]) =
          *(const float4*)(Kb + headoff + (size_t)(jt * 64 + r) * HDIM + c4);
      *(float4*)(&Vs[r][c4]) =
          *(const float4*)(Vb + headoff + (size_t)(jt * 64 + r) * HDIM + c4);
    }
    if (tid < 64) msk[tid] = imask[n * S_LEN + jt * 64 + tid];
    __syncthreads();

    const int tkey = jt * 64 + lane;
    const float mv = msk[lane];
    const float v0 = Vs[0][lane];

#pragma unroll
    for (int rg = 0; rg < 2; ++rg) {
      // ---- logits for 4 rows (lane = key) ----
      float acc[4];
#pragma unroll
      for (int rr = 0; rr < 4; ++rr) acc[rr] = 0.f;
#pragma unroll 2
      for (int d4 = 0; d4 < 16; ++d4) {
        const float4 k4 = *(const float4*)(&Ks[lane][d4 << 2]);
#pragma unroll
        for (int rr = 0; rr < 4; ++rr) {
          const float4 q4 =
              *(const float4*)(&Qs[(wave << 3) + (rg << 2) + rr][d4 << 2]);
          acc[rr] += k4.x * q4.x + k4.y * q4.y + k4.z * q4.z + k4.w * q4.w;
        }
      }

      float f63v[4], s0v[4];
#pragma unroll
      for (int rr = 0; rr < 4; ++rr) {
        const int ri = (rg << 2) + rr;
        const int srow = rb * 64 + (wave << 3) + ri;
        float a = (tkey <= srow) ? (mv / (1.0f + expf(-acc[rr]))) : 0.0f;
        float f = 1.0f - a + EPS_G;
        float p = f;
#pragma unroll
        for (int off = 1; off < 64; off <<= 1) {
          float v = __shfl_down(p, off);
          p *= (lane + off < 64) ? v : 1.0f;
        }
        float qprev = __shfl_up(p, 1);
        float c = (lane == 0) ? ((jt == 0) ? a : 0.0f)
                              : (a * qprev * Crow[ri]);
        cs[wave][rr][lane] = c;
        float ptile = __shfl(p, 0);
        float a0    = __shfl(a, 0);
        f63v[rr] = __shfl(f, 63);
        s0v[rr]  = a0 * ptile * Crow[ri];
        Crow[ri] *= ptile;
      }

      // ---- PV update (lane = dim) ----
#pragma unroll
      for (int rr = 0; rr < 4; ++rr)
        outv[(rg << 2) + rr] += pend[(rg << 2) + rr] * f63v[rr];
#pragma unroll 2
      for (int l4 = 0; l4 < 16; ++l4) {
        const float vv0 = Vs[(l4 << 2) + 0][lane];
        const float vv1 = Vs[(l4 << 2) + 1][lane];
        const float vv2 = Vs[(l4 << 2) + 2][lane];
        const float vv3 = Vs[(l4 << 2) + 3][lane];
#pragma unroll
        for (int rr = 0; rr < 4; ++rr) {
          const float4 c4 = *(const float4*)(&cs[wave][rr][l4 << 2]);
          outv[(rg << 2) + rr] += c4.x * vv0 + c4.y * vv1 + c4.z * vv2 + c4.w * vv3;
        }
      }
#pragma unroll
      for (int rr = 0; rr < 4; ++rr)
        pend[(rg << 2) + rr] = s0v[rr] * v0;
    }
  }

#pragma unroll
  for (int rr = 0; rr < 8; ++rr) {
    const int srow = rb * 64 + (wave << 3) + rr;
    att[(size_t)(n * S_LEN + srow) * DMODEL + h * HDIM + lane] = outv[rr];
  }
}

// ---------------------------------------------------------------------------
// Kernel 4: out = att @ Wo^T + bo
// ---------------------------------------------------------------------------
__global__ __launch_bounds__(256) void out_gemm(const float* __restrict__ Xa,
                                                const float* __restrict__ Wo,
                                                const float* __restrict__ bo,
                                                float* __restrict__ Out) {
  const int i0 = blockIdx.x << 6;
  const int j0 = blockIdx.y << 6;

  __shared__ float Xs[32][68];
  __shared__ float Ws[32][68];
  const int tid = threadIdx.x;
  const int tx = tid & 15, ty = tid >> 4;

  float acc[4][4];
#pragma unroll
  for (int i = 0; i < 4; ++i)
#pragma unroll
    for (int j = 0; j < 4; ++j) acc[i][j] = 0.f;

  for (int k0 = 0; k0 < 512; k0 += 32) {
    __syncthreads();
#pragma unroll
    for (int pass = 0; pass < 2; ++pass) {
      int idx = tid + (pass << 8);
      int r = idx >> 3, c4 = (idx & 7) << 2;
      float4 x4 = *(const float4*)(Xa + (size_t)(i0 + r) * 512 + k0 + c4);
      Xs[c4 + 0][r] = x4.x; Xs[c4 + 1][r] = x4.y; Xs[c4 + 2][r] = x4.z; Xs[c4 + 3][r] = x4.w;
      float4 w4 = *(const float4*)(Wo + (size_t)(j0 + r) * 512 + k0 + c4);
      Ws[c4 + 0][r] = w4.x; Ws[c4 + 1][r] = w4.y; Ws[c4 + 2][r] = w4.z; Ws[c4 + 3][r] = w4.w;
    }
    __syncthreads();
#pragma unroll
    for (int k = 0; k < 32; ++k) {
      float4 a4 = *(const float4*)(&Xs[k][ty << 2]);
      float4 b4 = *(const float4*)(&Ws[k][tx << 2]);
      float ar[4] = {a4.x, a4.y, a4.z, a4.w};
      float br[4] = {b4.x, b4.y, b4.z, b4.w};
#pragma unroll
      for (int ii = 0; ii < 4; ++ii)
#pragma unroll
        for (int jj = 0; jj < 4; ++jj) acc[ii][jj] += ar[ii] * br[jj];
    }
  }

  const float b0 = bo[j0 + (tx << 2) + 0];
  const float b1 = bo[j0 + (tx << 2) + 1];
  const float b2 = bo[j0 + (tx << 2) + 2];
  const float b3 = bo[j0 + (tx << 2) + 3];
#pragma unroll
  for (int ii = 0; ii < 4; ++ii) {
    float4 o;
    o.x = acc[ii][0] + b0; o.y = acc[ii][1] + b1;
    o.z = acc[ii][2] + b2; o.w = acc[ii][3] + b3;
    *(float4*)(Out + (size_t)(i0 + (ty << 2) + ii) * 512 + j0 + (tx << 2)) = o;
  }
}

// ---------------------------------------------------------------------------
extern "C" void kernel_launch(void* const* d_in, const int* in_sizes, int n_in,
                              void* d_out, int out_size, void* d_ws, size_t ws_size,
                              hipStream_t stream) {
  (void)in_sizes; (void)n_in; (void)out_size; (void)ws_size;
  const float* seq  = (const float*)d_in[0];
  const float* mask = (const float*)d_in[1];
  const int*   pos  = (const int*)d_in[2];
  const float* Wq = (const float*)d_in[4];
  const float* bq = (const float*)d_in[5];
  const float* Wk = (const float*)d_in[6];
  const float* bk = (const float*)d_in[7];
  const float* Wv = (const float*)d_in[8];
  const float* bv = (const float*)d_in[9];
  const float* Wo = (const float*)d_in[10];
  const float* bo = (const float*)d_in[11];
  float* out = (float*)d_out;

  float* ws = (float*)d_ws;
  const size_t HE = (size_t)16 * S_LEN * HDIM;
  float* Qb  = ws;
  float* Kb  = Qb + HE;
  float* Vb  = Kb + HE;
  float* att = Vb + HE;

  qkv_gemm<<<dim3(64, 24), 256, 0, stream>>>(seq, Wq, Wk, Wv, bq, bk, bv, Qb, Kb, Vb);
  xpos_kernel<<<4096, 256, 0, stream>>>(Qb, Kb, pos);
  attn_kernel<<<512, 512, 0, stream>>>(Qb, Kb, Vb, mask, att);
  out_gemm<<<dim3(64, 8), 256, 0, stream>>>(att, Wo, bo, out);
}

// Round 3
// 349.038 us; speedup vs baseline: 13.8276x; 1.6299x over previous
//
#include <hip/hip_runtime.h>
#include <math.h>

#define S_LEN 2048
#define DMODEL 512
#define HDIM 64
#define EPS_G 1e-8f

typedef __bf16 bf16x8 __attribute__((ext_vector_type(8)));
typedef __bf16 bf16x4 __attribute__((ext_vector_type(4)));
typedef float f32x4 __attribute__((ext_vector_type(4)));

// ---------------------------------------------------------------------------
// Kernel 1: fused QKV projection + xpos + bf16 conversion.
// out[i,j] = sum_k X[i,k]*W[j,k] + b[j].  BM=64,BN=64(one head),BK=32.
// Q/K: apply xpos rotary+scale in epilogue, store bf16 [nh][s][64].
// V: store bf16 TRANSPOSED [nh][d][s] (B-fragment-friendly for PV MFMA),
//    via an LDS bounce for coalesced global writes.
// ---------------------------------------------------------------------------
__global__ __launch_bounds__(256) void qkv_gemm(
    const float* __restrict__ X,
    const float* __restrict__ Wq, const float* __restrict__ Wk, const float* __restrict__ Wv,
    const float* __restrict__ bq, const float* __restrict__ bk, const float* __restrict__ bv,
    const int* __restrict__ pos,
    __bf16* __restrict__ Qh, __bf16* __restrict__ Kh, __bf16* __restrict__ Vt) {
  const int i0 = blockIdx.x << 6;
  const int jb = blockIdx.y;
  const int which = jb >> 3;
  const int h = jb & 7;
  const float* __restrict__ W    = (which == 0) ? Wq : (which == 1) ? Wk : Wv;
  const float* __restrict__ bias = (which == 0) ? bq : (which == 1) ? bk : bv;
  const int j0 = h << 6;

  __shared__ float Xs[32][68];
  __shared__ float Ws[32][68];
  __shared__ float Obuf[64][68];   // V transpose bounce (pitch 68: 16B-aligned rows)
  const int tid = threadIdx.x;
  const int tx = tid & 15, ty = tid >> 4;

  float acc[4][4];
#pragma unroll
  for (int i = 0; i < 4; ++i)
#pragma unroll
    for (int j = 0; j < 4; ++j) acc[i][j] = 0.f;

  for (int k0 = 0; k0 < 512; k0 += 32) {
    __syncthreads();
#pragma unroll
    for (int pass = 0; pass < 2; ++pass) {
      int idx = tid + (pass << 8);
      int r = idx >> 3, c4 = (idx & 7) << 2;
      float4 x4 = *(const float4*)(X + (size_t)(i0 + r) * 512 + k0 + c4);
      Xs[c4 + 0][r] = x4.x; Xs[c4 + 1][r] = x4.y; Xs[c4 + 2][r] = x4.z; Xs[c4 + 3][r] = x4.w;
      float4 w4 = *(const float4*)(W + (size_t)(j0 + r) * 512 + k0 + c4);
      Ws[c4 + 0][r] = w4.x; Ws[c4 + 1][r] = w4.y; Ws[c4 + 2][r] = w4.z; Ws[c4 + 3][r] = w4.w;
    }
    __syncthreads();
#pragma unroll
    for (int k = 0; k < 32; ++k) {
      float4 a4 = *(const float4*)(&Xs[k][ty << 2]);
      float4 b4 = *(const float4*)(&Ws[k][tx << 2]);
      float ar[4] = {a4.x, a4.y, a4.z, a4.w};
      float br[4] = {b4.x, b4.y, b4.z, b4.w};
#pragma unroll
      for (int ii = 0; ii < 4; ++ii)
#pragma unroll
        for (int jj = 0; jj < 4; ++jj) acc[ii][jj] += ar[ii] * br[jj];
    }
  }

  // bias
  float bv_[4];
#pragma unroll
  for (int jj = 0; jj < 4; ++jj) bv_[jj] = bias[j0 + (tx << 2) + jj];
#pragma unroll
  for (int ii = 0; ii < 4; ++ii)
#pragma unroll
    for (int jj = 0; jj < 4; ++jj) acc[ii][jj] += bv_[jj];

  const int n = i0 >> 11;
  const int sb = i0 & 2047;
  const int nh = (n << 3) + h;

  if (which < 2) {
    // xpos epilogue.  dims are cols tx*4..tx*4+3 = pairs kp = tx*2, tx*2+1
    const float qscale = (which == 0) ? 0.125f : 1.f;   // fused HEAD_DIM^-0.5
    const float sgn    = (which == 0) ? 1.f : -1.f;     // downscale for K
    __bf16* __restrict__ Ob = (which == 0) ? Qh : Kh;
#pragma unroll
    for (int ii = 0; ii < 4; ++ii) {
      const int srow = sb + (ty << 2) + ii;
      const float p = (float)pos[n * S_LEN + srow];
      bf16x4 o4;
#pragma unroll
      for (int c = 0; c < 2; ++c) {
        const float kpf = (float)((tx << 1) + c);
        const float inv_freq = exp2f(-0.41524100f * kpf);   // 10000^(-2k/64)
        const float ang = p * inv_freq;
        const float sn = sinf(ang), cn = cosf(ang);
        const float sv = (2.f * kpf + 25.6f) * (1.0f / 89.6f);
        const float e  = p * (1.0f / 512.0f) * log2f(sv);
        const float scl = exp2f(sgn * e) * qscale;
        const float x1 = acc[ii][2 * c], x2 = acc[ii][2 * c + 1];
        o4[2 * c]     = (__bf16)((x1 * cn - x2 * sn) * scl);
        o4[2 * c + 1] = (__bf16)((x2 * cn + x1 * sn) * scl);
      }
      *(bf16x4*)(Ob + ((size_t)nh * S_LEN + srow) * HDIM + (tx << 2)) = o4;
    }
  } else {
    // V: LDS transpose bounce, write Vt[nh*64+d][s] bf16
    __syncthreads();
#pragma unroll
    for (int ii = 0; ii < 4; ++ii)
      *(float4*)(&Obuf[(ty << 2) + ii][tx << 2]) = *(float4*)(&acc[ii][0]);
    __syncthreads();
    const int d = tid >> 2, part = tid & 3;
    __bf16 tmp[16];
#pragma unroll
    for (int i = 0; i < 16; ++i) tmp[i] = (__bf16)Obuf[part * 16 + i][d];
    __bf16* dst = Vt + ((size_t)(nh * 64 + d) << 11) + sb + part * 16;
    *(bf16x8*)(dst)     = *(bf16x8*)&tmp[0];
    *(bf16x8*)(dst + 8) = *(bf16x8*)&tmp[8];
  }
}

// ---------------------------------------------------------------------------
// Kernel 2: fused sigmoid-gated attention, MFMA edition.
// Block = (head nh, 64-query row block rb), 4 waves; wave owns a 16-query
// strip.  Per 64-key tile (serial, keys high->low):
//   QK^T: 8x mfma_f32_16x16x32_bf16 (A=Q: m=query, B=K: n=key)
//         D layout: query=(lane>>4)*4+reg, key=lane&15 (+16*nt)
//   gate scan: 16-key segment suffix products (4 shuffle-muls) + cross-
//         segment tails; exact generalization of the R1-verified scan.
//   coefficients -> bf16 via LDS (wave-private rows) -> A-fragment for PV.
//   PV: 8x mfma against LDS V^T (rows=dim) so B-frags are ds_read_b128.
//   Tile-boundary column t0 handled by R1's VALU pending rank-1 update.
// ---------------------------------------------------------------------------
__global__ __launch_bounds__(256, 2) void attn_kernel(
    const __bf16* __restrict__ Qh, const __bf16* __restrict__ Kh,
    const __bf16* __restrict__ Vt, const float* __restrict__ imask,
    float* __restrict__ att) {
  const int id = blockIdx.x;
  const int nh = id >> 5;
  const int rbi = id & 31;
  const int rb = (id < 256) ? rbi : (31 - rbi);   // heavy+light pairing
  const int n = nh >> 3;
  const int h = nh & 7;
  const int tid = threadIdx.x;
  const int wv = tid >> 6;
  const int lane = tid & 63;
  const int l = lane & 15;          // key-in-segment / m or n index
  const int seg = lane >> 4;        // quad
  const int segb = lane & 48;       // first lane of segment

  __shared__ __bf16 Qs16[64][72];   // [query][dim]   pitch 72 -> 2-way banks
  __shared__ __bf16 Ks16[64][72];   // [key][dim]
  __shared__ __bf16 Vt16[64][72];   // [dim][key]  (transposed V tile)
  __shared__ __bf16 cs16[64][72];   // coefficient matrix [query][key], wave-private rows
  __shared__ float msk[64];

  // stage Q strip block once
  for (int idx = tid; idx < 512; idx += 256) {
    int r = idx >> 3, c8 = (idx & 7) << 3;
    *(bf16x8*)&Qs16[r][c8] =
        *(const bf16x8*)(Qh + (((size_t)nh * S_LEN + rb * 64 + r) << 6) + c8);
  }

  f32x4 O[4];                       // O[nt][reg]: query=(seg*4+reg), dim=nt*16+l
  float pend[4][4];                 // pending rank-1 [reg][nt]
  float Crow[4];
#pragma unroll
  for (int nt = 0; nt < 4; ++nt) { O[nt] = (f32x4){0.f, 0.f, 0.f, 0.f}; }
#pragma unroll
  for (int r = 0; r < 4; ++r) {
    Crow[r] = 1.f;
#pragma unroll
    for (int nt = 0; nt < 4; ++nt) pend[r][nt] = 0.f;
  }

  for (int jt = rb; jt >= 0; --jt) {
    __syncthreads();
    for (int idx = tid; idx < 512; idx += 256) {
      int r = idx >> 3, c8 = (idx & 7) << 3;
      *(bf16x8*)&Ks16[r][c8] =
          *(const bf16x8*)(Kh + (((size_t)nh * S_LEN + jt * 64 + r) << 6) + c8);
      *(bf16x8*)&Vt16[r][c8] =
          *(const bf16x8*)(Vt + (((size_t)nh * 64 + r) << 11) + jt * 64 + c8);
    }
    if (tid < 64) msk[tid] = imask[n * S_LEN + jt * 64 + tid];
    __syncthreads();

    // ---- QK^T MFMAs ----
    bf16x8 aq0 = *(const bf16x8*)&Qs16[wv * 16 + l][seg * 8];
    bf16x8 aq1 = *(const bf16x8*)&Qs16[wv * 16 + l][seg * 8 + 32];
    f32x4 Sv[4];
#pragma unroll
    for (int nt = 0; nt < 4; ++nt) {
      bf16x8 bk0 = *(const bf16x8*)&Ks16[nt * 16 + l][seg * 8];
      bf16x8 bk1 = *(const bf16x8*)&Ks16[nt * 16 + l][seg * 8 + 32];
      f32x4 z = (f32x4){0.f, 0.f, 0.f, 0.f};
      z = __builtin_amdgcn_mfma_f32_16x16x32_bf16(aq0, bk0, z, 0, 0, 0);
      z = __builtin_amdgcn_mfma_f32_16x16x32_bf16(aq1, bk1, z, 0, 0, 0);
      Sv[nt] = z;
    }

    // V column t0 (for pending), per output dim
    float v0f[4];
#pragma unroll
    for (int nt = 0; nt < 4; ++nt) v0f[nt] = (float)Vt16[nt * 16 + l][0];

    // ---- gate scan + coefficient write, per query row (reg) ----
#pragma unroll
    for (int reg = 0; reg < 4; ++reg) {
      const int qrow = rb * 64 + wv * 16 + seg * 4 + reg;
      float a_[4], f_[4], p_[4], P_[4];
#pragma unroll
      for (int nt = 0; nt < 4; ++nt) {
        const int key = jt * 64 + nt * 16 + l;
        const float s = Sv[nt][reg];
        const float mv = msk[nt * 16 + l];
        const float av = (key <= qrow) ? (mv / (1.f + expf(-s))) : 0.f;
        a_[nt] = av;
        f_[nt] = 1.f - av + EPS_G;
      }
      // segment-local inclusive suffix products
#pragma unroll
      for (int nt = 0; nt < 4; ++nt) {
        float p = f_[nt];
#pragma unroll
        for (int off = 1; off < 16; off <<= 1) {
          float v = __shfl(p, lane + off);
          p *= ((l + off) < 16) ? v : 1.f;
        }
        p_[nt] = p;
        P_[nt] = __shfl(p, segb);            // whole-segment product
      }
      const float T3 = 1.f, T2 = P_[3], T1 = T2 * P_[2], T0 = T1 * P_[1];
      const float Tarr[4] = {T0, T1, T2, T3}; // product of segments above nt
      const float Ptile = T0 * P_[0];
      const float crow = Crow[reg];
#pragma unroll
      for (int nt = 0; nt < 4; ++nt) {
        const float pprev = __shfl(p_[nt], lane - 1);           // p[l-1], l>=1
        const float f15p = (nt > 0) ? __shfl(f_[nt - 1], segb + 15) : 0.f;
        float cv;
        if (l > 0)
          cv = a_[nt] * pprev * Tarr[nt] * crow;
        else if (nt > 0)
          cv = a_[nt] * f15p * P_[nt] * Tarr[nt] * crow;
        else
          cv = (jt == 0) ? a_[0] : 0.f;       // t0 column: pending (or s==0 ones-col)
        cs16[wv * 16 + seg * 4 + reg][nt * 16 + l] = (__bf16)cv;
      }
      const float a0  = __shfl(a_[0], segb);
      const float f63 = __shfl(f_[3], segb + 15);
      const float s0  = a0 * Ptile * crow;
      Crow[reg] = crow * Ptile;
#pragma unroll
      for (int nt = 0; nt < 4; ++nt) {
        O[nt][reg] += pend[reg][nt] * f63;    // resolve previous tile's t0
        pend[reg][nt] = s0 * v0f[nt];         // new pending for this tile's t0
      }
    }

    // ---- PV MFMAs (cs rows are wave-private; compiler orders LDS RAW) ----
    bf16x8 ac0 = *(const bf16x8*)&cs16[wv * 16 + l][seg * 8];
    bf16x8 ac1 = *(const bf16x8*)&cs16[wv * 16 + l][seg * 8 + 32];
#pragma unroll
    for (int nt = 0; nt < 4; ++nt) {
      bf16x8 bv0 = *(const bf16x8*)&Vt16[nt * 16 + l][seg * 8];
      bf16x8 bv1 = *(const bf16x8*)&Vt16[nt * 16 + l][seg * 8 + 32];
      O[nt] = __builtin_amdgcn_mfma_f32_16x16x32_bf16(ac0, bv0, O[nt], 0, 0, 0);
      O[nt] = __builtin_amdgcn_mfma_f32_16x16x32_bf16(ac1, bv1, O[nt], 0, 0, 0);
    }
  }

  // epilogue: att[(n, s, h*64+d)] f32
#pragma unroll
  for (int nt = 0; nt < 4; ++nt)
#pragma unroll
    for (int reg = 0; reg < 4; ++reg) {
      const int srow = rb * 64 + wv * 16 + seg * 4 + reg;
      const int d = nt * 16 + l;
      att[((size_t)(n * S_LEN + srow)) * DMODEL + h * HDIM + d] = O[nt][reg];
    }
}

// ---------------------------------------------------------------------------
// Kernel 3: out = att @ Wo^T + bo
// ---------------------------------------------------------------------------
__global__ __launch_bounds__(256) void out_gemm(const float* __restrict__ Xa,
                                                const float* __restrict__ Wo,
                                                const float* __restrict__ bo,
                                                float* __restrict__ Out) {
  const int i0 = blockIdx.x << 6;
  const int j0 = blockIdx.y << 6;

  __shared__ float Xs[32][68];
  __shared__ float Ws[32][68];
  const int tid = threadIdx.x;
  const int tx = tid & 15, ty = tid >> 4;

  float acc[4][4];
#pragma unroll
  for (int i = 0; i < 4; ++i)
#pragma unroll
    for (int j = 0; j < 4; ++j) acc[i][j] = 0.f;

  for (int k0 = 0; k0 < 512; k0 += 32) {
    __syncthreads();
#pragma unroll
    for (int pass = 0; pass < 2; ++pass) {
      int idx = tid + (pass << 8);
      int r = idx >> 3, c4 = (idx & 7) << 2;
      float4 x4 = *(const float4*)(Xa + (size_t)(i0 + r) * 512 + k0 + c4);
      Xs[c4 + 0][r] = x4.x; Xs[c4 + 1][r] = x4.y; Xs[c4 + 2][r] = x4.z; Xs[c4 + 3][r] = x4.w;
      float4 w4 = *(const float4*)(Wo + (size_t)(j0 + r) * 512 + k0 + c4);
      Ws[c4 + 0][r] = w4.x; Ws[c4 + 1][r] = w4.y; Ws[c4 + 2][r] = w4.z; Ws[c4 + 3][r] = w4.w;
    }
    __syncthreads();
#pragma unroll
    for (int k = 0; k < 32; ++k) {
      float4 a4 = *(const float4*)(&Xs[k][ty << 2]);
      float4 b4 = *(const float4*)(&Ws[k][tx << 2]);
      float ar[4] = {a4.x, a4.y, a4.z, a4.w};
      float br[4] = {b4.x, b4.y, b4.z, b4.w};
#pragma unroll
      for (int ii = 0; ii < 4; ++ii)
#pragma unroll
        for (int jj = 0; jj < 4; ++jj) acc[ii][jj] += ar[ii] * br[jj];
    }
  }

  const float b0 = bo[j0 + (tx << 2) + 0];
  const float b1 = bo[j0 + (tx << 2) + 1];
  const float b2 = bo[j0 + (tx << 2) + 2];
  const float b3 = bo[j0 + (tx << 2) + 3];
#pragma unroll
  for (int ii = 0; ii < 4; ++ii) {
    float4 o;
    o.x = acc[ii][0] + b0; o.y = acc[ii][1] + b1;
    o.z = acc[ii][2] + b2; o.w = acc[ii][3] + b3;
    *(float4*)(Out + (size_t)(i0 + (ty << 2) + ii) * 512 + j0 + (tx << 2)) = o;
  }
}

// ---------------------------------------------------------------------------
extern "C" void kernel_launch(void* const* d_in, const int* in_sizes, int n_in,
                              void* d_out, int out_size, void* d_ws, size_t ws_size,
                              hipStream_t stream) {
  (void)in_sizes; (void)n_in; (void)out_size; (void)ws_size;
  const float* seq  = (const float*)d_in[0];
  const float* mask = (const float*)d_in[1];
  const int*   pos  = (const int*)d_in[2];
  const float* Wq = (const float*)d_in[4];
  const float* bq = (const float*)d_in[5];
  const float* Wk = (const float*)d_in[6];
  const float* bk = (const float*)d_in[7];
  const float* Wv = (const float*)d_in[8];
  const float* bv = (const float*)d_in[9];
  const float* Wo = (const float*)d_in[10];
  const float* bo = (const float*)d_in[11];
  float* out = (float*)d_out;

  char* base = (char*)d_ws;
  float*  att = (float*)base;                          // 8 MB  (4096 x 512 f32)
  __bf16* Qh  = (__bf16*)(base + (8u << 20));          // 4 MB  [nh][s][64]
  __bf16* Kh  = (__bf16*)(base + (12u << 20));         // 4 MB  [nh][s][64]
  __bf16* Vt  = (__bf16*)(base + (16u << 20));         // 4 MB  [nh][d][2048]

  qkv_gemm<<<dim3(64, 24), 256, 0, stream>>>(seq, Wq, Wk, Wv, bq, bk, bv, pos, Qh, Kh, Vt);
  attn_kernel<<<512, 256, 0, stream>>>(Qh, Kh, Vt, mask, att);
  out_gemm<<<dim3(64, 8), 256, 0, stream>>>(att, Wo, bo, out);
}

// Round 4
// 271.997 us; speedup vs baseline: 17.7442x; 1.2832x over previous
//
#include <hip/hip_runtime.h>
#include <math.h>

#define S_LEN 2048
#define DMODEL 512
#define HDIM 64
#define EPS_G 1e-8f

typedef __bf16 bf16x8 __attribute__((ext_vector_type(8)));
typedef float f32x4 __attribute__((ext_vector_type(4)));

__device__ __forceinline__ bf16x8 cvt2(const float4 a, const float4 b) {
  bf16x8 r;
  r[0] = (__bf16)a.x; r[1] = (__bf16)a.y; r[2] = (__bf16)a.z; r[3] = (__bf16)a.w;
  r[4] = (__bf16)b.x; r[5] = (__bf16)b.y; r[6] = (__bf16)b.z; r[7] = (__bf16)b.w;
  return r;
}

// ---------------------------------------------------------------------------
// Kernel 1: fused QKV projection (bf16 MFMA) + xpos + layout conversion.
// Tile: 64(M rows of X) x 64(N = one head's dims), K staged 64 at a time,
// f32->bf16 converted into LDS.  MFMA layouts as verified in R3 attn:
//   A[m][k]: m=lane&15, k=(lane>>4)*8+j (2 chained MFMAs for K=64)
//   D[m][n]: m=seg*4+reg, n=lane&15 (+16*nt)
// Q/K epilogue: bias + xpos (partner dim via __shfl_xor 1) -> bf16 [nh][s][64]
// V epilogue: bias -> bf16 transposed [nh][d][s] via LDS bounce.
// ---------------------------------------------------------------------------
__global__ __launch_bounds__(256) void qkv_gemm(
    const float* __restrict__ X,
    const float* __restrict__ Wq, const float* __restrict__ Wk, const float* __restrict__ Wv,
    const float* __restrict__ bq, const float* __restrict__ bk, const float* __restrict__ bv,
    const int* __restrict__ pos,
    __bf16* __restrict__ Qh, __bf16* __restrict__ Kh, __bf16* __restrict__ Vt) {
  const int i0 = blockIdx.x << 6;
  const int jb = blockIdx.y;
  const int which = jb >> 3, h = jb & 7;
  const float* __restrict__ W    = (which == 0) ? Wq : (which == 1) ? Wk : Wv;
  const float* __restrict__ bias = (which == 0) ? bq : (which == 1) ? bk : bv;
  const int j0 = h << 6;

  __shared__ __bf16 As[64][72];
  __shared__ __bf16 Bs[64][72];

  const int tid = threadIdx.x;
  const int wv = tid >> 6, lane = tid & 63;
  const int l = lane & 15, seg = lane >> 4;
  const int sr = tid >> 2, sc = (tid & 3) << 4;   // staging row / col

  f32x4 O[4];
#pragma unroll
  for (int nt = 0; nt < 4; ++nt) O[nt] = (f32x4){0.f, 0.f, 0.f, 0.f};

  for (int k0 = 0; k0 < 512; k0 += 64) {
    __syncthreads();
    const float* xp = X + (size_t)(i0 + sr) * 512 + k0 + sc;
    float4 x0 = *(const float4*)xp,       x1 = *(const float4*)(xp + 4),
           x2 = *(const float4*)(xp + 8), x3 = *(const float4*)(xp + 12);
    *(bf16x8*)&As[sr][sc]     = cvt2(x0, x1);
    *(bf16x8*)&As[sr][sc + 8] = cvt2(x2, x3);
    const float* wp = W + (size_t)(j0 + sr) * 512 + k0 + sc;
    float4 w0 = *(const float4*)wp,       w1 = *(const float4*)(wp + 4),
           w2 = *(const float4*)(wp + 8), w3 = *(const float4*)(wp + 12);
    *(bf16x8*)&Bs[sr][sc]     = cvt2(w0, w1);
    *(bf16x8*)&Bs[sr][sc + 8] = cvt2(w2, w3);
    __syncthreads();
    bf16x8 a0 = *(const bf16x8*)&As[wv * 16 + l][seg * 8];
    bf16x8 a1 = *(const bf16x8*)&As[wv * 16 + l][seg * 8 + 32];
#pragma unroll
    for (int nt = 0; nt < 4; ++nt) {
      bf16x8 b0 = *(const bf16x8*)&Bs[nt * 16 + l][seg * 8];
      bf16x8 b1 = *(const bf16x8*)&Bs[nt * 16 + l][seg * 8 + 32];
      O[nt] = __builtin_amdgcn_mfma_f32_16x16x32_bf16(a0, b0, O[nt], 0, 0, 0);
      O[nt] = __builtin_amdgcn_mfma_f32_16x16x32_bf16(a1, b1, O[nt], 0, 0, 0);
    }
  }

#pragma unroll
  for (int nt = 0; nt < 4; ++nt) {
    const float bb = bias[j0 + nt * 16 + l];
#pragma unroll
    for (int reg = 0; reg < 4; ++reg) O[nt][reg] += bb;
  }

  const int n = i0 >> 11, sb = i0 & 2047;
  const int nh = (n << 3) + h;

  __syncthreads();   // Bs becomes the epilogue bounce buffer

  if (which < 2) {
    const float qs  = (which == 0) ? 0.125f : 1.f;   // fused HEAD_DIM^-0.5
    const float sgn = (which == 0) ? 1.f : -1.f;     // downscale for K
    __bf16* __restrict__ Ob = (which == 0) ? Qh : Kh;
    float invf[4], l2sv[4];
#pragma unroll
    for (int nt = 0; nt < 4; ++nt) {
      const float kp = (float)((nt * 16 + l) >> 1);
      invf[nt] = exp2f(-0.41524100f * kp);                 // 10000^(-2k/64)
      l2sv[nt] = log2f((2.f * kp + 25.6f) * (1.f / 89.6f));
    }
#pragma unroll
    for (int reg = 0; reg < 4; ++reg) {
      const int sl = wv * 16 + seg * 4 + reg;
      const float p = (float)pos[n * S_LEN + sb + sl];
#pragma unroll
      for (int nt = 0; nt < 4; ++nt) {
        const float x  = O[nt][reg];
        const float xp = __shfl_xor(x, 1);               // partner dim d^1
        const float ang = p * invf[nt];
        const float sn = sinf(ang), cn = cosf(ang);
        const float scl = exp2f(sgn * p * (1.f / 512.f) * l2sv[nt]) * qs;
        const int d = nt * 16 + l;
        const float o = (d & 1) ? (x * cn + xp * sn) : (x * cn - xp * sn);
        Bs[sl][d] = (__bf16)(o * scl);
      }
    }
    __syncthreads();
    __bf16* dst = Ob + (((size_t)nh * S_LEN + sb + sr) << 6) + sc;
    *(bf16x8*)dst       = *(bf16x8*)&Bs[sr][sc];
    *(bf16x8*)(dst + 8) = *(bf16x8*)&Bs[sr][sc + 8];
  } else {
#pragma unroll
    for (int reg = 0; reg < 4; ++reg) {
      const int sl = wv * 16 + seg * 4 + reg;
#pragma unroll
      for (int nt = 0; nt < 4; ++nt)
        Bs[sl][nt * 16 + l] = (__bf16)O[nt][reg];
    }
    __syncthreads();
    const int d = tid >> 2, part = tid & 3;
    __bf16 tmp[16];
#pragma unroll
    for (int i = 0; i < 16; ++i) tmp[i] = Bs[part * 16 + i][d];
    __bf16* dst = Vt + (((size_t)(nh * 64 + d)) << 11) + sb + part * 16;
    *(bf16x8*)dst       = *(bf16x8*)&tmp[0];
    *(bf16x8*)(dst + 8) = *(bf16x8*)&tmp[8];
  }
}

// ---------------------------------------------------------------------------
// Kernel 2: fused sigmoid-gated attention (R3 core) + LPT dynamic work queue
// + fast sigmoid (v_exp + v_rcp instead of libm expf + full-precision div).
// Work item = (nh, rb), sorted heavy-first: rb = 31 - (item>>4), nh = item&15.
// 1024 blocks pull items from an atomic counter -> near-optimal makespan and
// 4 co-resident blocks/CU (LDS-capped) for latency hiding.
// ---------------------------------------------------------------------------
__global__ __launch_bounds__(256, 2) void attn_kernel(
    const __bf16* __restrict__ Qh, const __bf16* __restrict__ Kh,
    const __bf16* __restrict__ Vt, const float* __restrict__ imask,
    float* __restrict__ att, int* __restrict__ cnt) {
  const int tid = threadIdx.x;
  const int wv = tid >> 6, lane = tid & 63;
  const int l = lane & 15, seg = lane >> 4, segb = lane & 48;

  __shared__ __bf16 Qs16[64][72];
  __shared__ __bf16 Ks16[64][72];
  __shared__ __bf16 Vt16[64][72];
  __shared__ __bf16 cs16[64][72];
  __shared__ float msk[64];
  __shared__ int s_item;

  for (;;) {
    __syncthreads();                       // previous item fully drained
    if (tid == 0) s_item = atomicAdd(cnt, 1);
    __syncthreads();
    const int item = s_item;
    if (item >= 512) break;
    const int rb = 31 - (item >> 4);       // heavy items first (LPT)
    const int nh = item & 15;
    const int n = nh >> 3, h = nh & 7;
    const size_t headoff = (size_t)nh * S_LEN * HDIM;

    for (int idx = tid; idx < 512; idx += 256) {
      int r = idx >> 3, c8 = (idx & 7) << 3;
      *(bf16x8*)&Qs16[r][c8] =
          *(const bf16x8*)(Qh + (((size_t)nh * S_LEN + rb * 64 + r) << 6) + c8);
    }

    f32x4 O[4];
    float pend[4][4];
    float Crow[4];
#pragma unroll
    for (int nt = 0; nt < 4; ++nt) O[nt] = (f32x4){0.f, 0.f, 0.f, 0.f};
#pragma unroll
    for (int r = 0; r < 4; ++r) {
      Crow[r] = 1.f;
#pragma unroll
      for (int nt = 0; nt < 4; ++nt) pend[r][nt] = 0.f;
    }

    for (int jt = rb; jt >= 0; --jt) {
      __syncthreads();
      for (int idx = tid; idx < 512; idx += 256) {
        int r = idx >> 3, c8 = (idx & 7) << 3;
        *(bf16x8*)&Ks16[r][c8] =
            *(const bf16x8*)(Kh + (((size_t)nh * S_LEN + jt * 64 + r) << 6) + c8);
        *(bf16x8*)&Vt16[r][c8] =
            *(const bf16x8*)(Vt + (((size_t)nh * 64 + r) << 11) + jt * 64 + c8);
      }
      if (tid < 64) msk[tid] = imask[n * S_LEN + jt * 64 + tid];
      __syncthreads();

      // ---- QK^T MFMAs ----
      bf16x8 aq0 = *(const bf16x8*)&Qs16[wv * 16 + l][seg * 8];
      bf16x8 aq1 = *(const bf16x8*)&Qs16[wv * 16 + l][seg * 8 + 32];
      f32x4 Sv[4];
#pragma unroll
      for (int nt = 0; nt < 4; ++nt) {
        bf16x8 bk0 = *(const bf16x8*)&Ks16[nt * 16 + l][seg * 8];
        bf16x8 bk1 = *(const bf16x8*)&Ks16[nt * 16 + l][seg * 8 + 32];
        f32x4 z = (f32x4){0.f, 0.f, 0.f, 0.f};
        z = __builtin_amdgcn_mfma_f32_16x16x32_bf16(aq0, bk0, z, 0, 0, 0);
        z = __builtin_amdgcn_mfma_f32_16x16x32_bf16(aq1, bk1, z, 0, 0, 0);
        Sv[nt] = z;
      }

      float v0f[4];
#pragma unroll
      for (int nt = 0; nt < 4; ++nt) v0f[nt] = (float)Vt16[nt * 16 + l][0];

      // ---- gate scan + coefficients, per query row ----
#pragma unroll
      for (int reg = 0; reg < 4; ++reg) {
        const int qrow = rb * 64 + wv * 16 + seg * 4 + reg;
        float a_[4], f_[4], p_[4], P_[4];
#pragma unroll
        for (int nt = 0; nt < 4; ++nt) {
          const int key = jt * 64 + nt * 16 + l;
          const float s = Sv[nt][reg];
          const float mv = msk[nt * 16 + l];
          const float av = (key <= qrow)
              ? mv * __builtin_amdgcn_rcpf(1.f + __expf(-s))
              : 0.f;
          a_[nt] = av;
          f_[nt] = 1.f - av + EPS_G;
        }
#pragma unroll
        for (int nt = 0; nt < 4; ++nt) {
          float p = f_[nt];
#pragma unroll
          for (int off = 1; off < 16; off <<= 1) {
            float v = __shfl(p, lane + off);
            p *= ((l + off) < 16) ? v : 1.f;
          }
          p_[nt] = p;
          P_[nt] = __shfl(p, segb);
        }
        const float T3 = 1.f, T2 = P_[3], T1 = T2 * P_[2], T0 = T1 * P_[1];
        const float Tarr[4] = {T0, T1, T2, T3};
        const float Ptile = T0 * P_[0];
        const float crow = Crow[reg];
#pragma unroll
        for (int nt = 0; nt < 4; ++nt) {
          const float pprev = __shfl(p_[nt], lane - 1);
          const float f15p = (nt > 0) ? __shfl(f_[nt - 1], segb + 15) : 0.f;
          float cv;
          if (l > 0)
            cv = a_[nt] * pprev * Tarr[nt] * crow;
          else if (nt > 0)
            cv = a_[nt] * f15p * P_[nt] * Tarr[nt] * crow;
          else
            cv = (jt == 0) ? a_[0] : 0.f;
          cs16[wv * 16 + seg * 4 + reg][nt * 16 + l] = (__bf16)cv;
        }
        const float a0  = __shfl(a_[0], segb);
        const float f63 = __shfl(f_[3], segb + 15);
        const float s0  = a0 * Ptile * crow;
        Crow[reg] = crow * Ptile;
#pragma unroll
        for (int nt = 0; nt < 4; ++nt) {
          O[nt][reg] += pend[reg][nt] * f63;
          pend[reg][nt] = s0 * v0f[nt];
        }
      }

      // ---- PV MFMAs ----
      bf16x8 ac0 = *(const bf16x8*)&cs16[wv * 16 + l][seg * 8];
      bf16x8 ac1 = *(const bf16x8*)&cs16[wv * 16 + l][seg * 8 + 32];
#pragma unroll
      for (int nt = 0; nt < 4; ++nt) {
        bf16x8 bv0 = *(const bf16x8*)&Vt16[nt * 16 + l][seg * 8];
        bf16x8 bv1 = *(const bf16x8*)&Vt16[nt * 16 + l][seg * 8 + 32];
        O[nt] = __builtin_amdgcn_mfma_f32_16x16x32_bf16(ac0, bv0, O[nt], 0, 0, 0);
        O[nt] = __builtin_amdgcn_mfma_f32_16x16x32_bf16(ac1, bv1, O[nt], 0, 0, 0);
      }
    }

    // epilogue: att[(n, s, h*64+d)] f32
#pragma unroll
    for (int nt = 0; nt < 4; ++nt)
#pragma unroll
      for (int reg = 0; reg < 4; ++reg) {
        const int srow = rb * 64 + wv * 16 + seg * 4 + reg;
        const int d = nt * 16 + l;
        att[((size_t)(n * S_LEN + srow)) * DMODEL + h * HDIM + d] = O[nt][reg];
      }
  }
}

// ---------------------------------------------------------------------------
// Kernel 3: out = att @ Wo^T + bo  (bf16 MFMA, same structure as kernel 1)
// ---------------------------------------------------------------------------
__global__ __launch_bounds__(256) void out_gemm(const float* __restrict__ Xa,
                                                const float* __restrict__ Wo,
                                                const float* __restrict__ bo,
                                                float* __restrict__ Out) {
  const int i0 = blockIdx.x << 6, j0 = blockIdx.y << 6;
  __shared__ __bf16 As[64][72];
  __shared__ __bf16 Bs[64][72];

  const int tid = threadIdx.x;
  const int wv = tid >> 6, lane = tid & 63;
  const int l = lane & 15, seg = lane >> 4;
  const int sr = tid >> 2, sc = (tid & 3) << 4;

  f32x4 O[4];
#pragma unroll
  for (int nt = 0; nt < 4; ++nt) O[nt] = (f32x4){0.f, 0.f, 0.f, 0.f};

  for (int k0 = 0; k0 < 512; k0 += 64) {
    __syncthreads();
    const float* xp = Xa + (size_t)(i0 + sr) * 512 + k0 + sc;
    float4 x0 = *(const float4*)xp,       x1 = *(const float4*)(xp + 4),
           x2 = *(const float4*)(xp + 8), x3 = *(const float4*)(xp + 12);
    *(bf16x8*)&As[sr][sc]     = cvt2(x0, x1);
    *(bf16x8*)&As[sr][sc + 8] = cvt2(x2, x3);
    const float* wp = Wo + (size_t)(j0 + sr) * 512 + k0 + sc;
    float4 w0 = *(const float4*)wp,       w1 = *(const float4*)(wp + 4),
           w2 = *(const float4*)(wp + 8), w3 = *(const float4*)(wp + 12);
    *(bf16x8*)&Bs[sr][sc]     = cvt2(w0, w1);
    *(bf16x8*)&Bs[sr][sc + 8] = cvt2(w2, w3);
    __syncthreads();
    bf16x8 a0 = *(const bf16x8*)&As[wv * 16 + l][seg * 8];
    bf16x8 a1 = *(const bf16x8*)&As[wv * 16 + l][seg * 8 + 32];
#pragma unroll
    for (int nt = 0; nt < 4; ++nt) {
      bf16x8 b0 = *(const bf16x8*)&Bs[nt * 16 + l][seg * 8];
      bf16x8 b1 = *(const bf16x8*)&Bs[nt * 16 + l][seg * 8 + 32];
      O[nt] = __builtin_amdgcn_mfma_f32_16x16x32_bf16(a0, b0, O[nt], 0, 0, 0);
      O[nt] = __builtin_amdgcn_mfma_f32_16x16x32_bf16(a1, b1, O[nt], 0, 0, 0);
    }
  }

#pragma unroll
  for (int nt = 0; nt < 4; ++nt) {
    const float bb = bo[j0 + nt * 16 + l];
#pragma unroll
    for (int reg = 0; reg < 4; ++reg) {
      const int m = wv * 16 + seg * 4 + reg;
      Out[(size_t)(i0 + m) * 512 + j0 + nt * 16 + l] = O[nt][reg] + bb;
    }
  }
}

// ---------------------------------------------------------------------------
extern "C" void kernel_launch(void* const* d_in, const int* in_sizes, int n_in,
                              void* d_out, int out_size, void* d_ws, size_t ws_size,
                              hipStream_t stream) {
  (void)in_sizes; (void)n_in; (void)out_size; (void)ws_size;
  const float* seq  = (const float*)d_in[0];
  const float* mask = (const float*)d_in[1];
  const int*   pos  = (const int*)d_in[2];
  const float* Wq = (const float*)d_in[4];
  const float* bq = (const float*)d_in[5];
  const float* Wk = (const float*)d_in[6];
  const float* bk = (const float*)d_in[7];
  const float* Wv = (const float*)d_in[8];
  const float* bv = (const float*)d_in[9];
  const float* Wo = (const float*)d_in[10];
  const float* bo = (const float*)d_in[11];
  float* out = (float*)d_out;

  char* base = (char*)d_ws;
  float*  att = (float*)base;                     // 8 MB  (4096 x 512 f32)
  __bf16* Qh  = (__bf16*)(base + (8u  << 20));    // 4 MB  [nh][s][64]
  __bf16* Kh  = (__bf16*)(base + (12u << 20));    // 4 MB  [nh][s][64]
  __bf16* Vt  = (__bf16*)(base + (16u << 20));    // 4 MB  [nh][d][2048]
  int*    cnt = (int*)(base + (20u << 20));       // work-queue counter

  hipMemsetAsync(cnt, 0, 64, stream);
  qkv_gemm<<<dim3(64, 24), 256, 0, stream>>>(seq, Wq, Wk, Wv, bq, bk, bv, pos, Qh, Kh, Vt);
  attn_kernel<<<1024, 256, 0, stream>>>(Qh, Kh, Vt, mask, att, cnt);
  out_gemm<<<dim3(64, 8), 256, 0, stream>>>(att, Wo, bo, out);
}

// Round 5
// 223.277 us; speedup vs baseline: 21.6161x; 1.2182x over previous
//
#include <hip/hip_runtime.h>
#include <math.h>

#define S_LEN 2048
#define DMODEL 512
#define HDIM 64
#define EPS_G 1e-8f

typedef __bf16 bf16x8 __attribute__((ext_vector_type(8)));
typedef float f32x4 __attribute__((ext_vector_type(4)));

__device__ __forceinline__ bf16x8 cvt2(const float4 a, const float4 b) {
  bf16x8 r;
  r[0] = (__bf16)a.x; r[1] = (__bf16)a.y; r[2] = (__bf16)a.z; r[3] = (__bf16)a.w;
  r[4] = (__bf16)b.x; r[5] = (__bf16)b.y; r[6] = (__bf16)b.z; r[7] = (__bf16)b.w;
  return r;
}

// DPP lane move within 16-lane rows: lane l gets src[l+N] (row_shl) or src[l-N]
// (row_shr); out-of-row lanes receive `oldv` (bound_ctrl=false keeps old).
template <int CTRL>
__device__ __forceinline__ float dpp_mov(float src, float oldv) {
  return __int_as_float(__builtin_amdgcn_update_dpp(
      __float_as_int(oldv), __float_as_int(src), CTRL, 0xF, 0xF, false));
}
#define ROW_SHL(n) (0x100 + (n))
#define ROW_SHR(n) (0x110 + (n))

// ds_swizzle BitMode: src_lane = ((lane & and) | or) ^ xor  (per 32-lane half)
// 0x0010: and=0x10 -> row head (lane segb).  0x01F0: and=0x10,or=0xF -> row tail.
__device__ __forceinline__ float swz_head(float v) {
  return __int_as_float(__builtin_amdgcn_ds_swizzle(__float_as_int(v), 0x0010));
}
__device__ __forceinline__ float swz_tail(float v) {
  return __int_as_float(__builtin_amdgcn_ds_swizzle(__float_as_int(v), 0x01F0));
}

// ---------------------------------------------------------------------------
// Kernel 1: fused QKV projection (bf16 MFMA) + xpos + layout conversion.
//   A[m][k]: m=lane&15, k=(lane>>4)*8+j ; D[m][n]: m=seg*4+reg, n=lane&15+16*nt
// Q/K epilogue: bias + xpos (partner dim via __shfl_xor 1) -> bf16 [nh][s][64]
// V epilogue: bias -> bf16 transposed [nh][d][s] via LDS bounce.
// ---------------------------------------------------------------------------
__global__ __launch_bounds__(256) void qkv_gemm(
    const float* __restrict__ X,
    const float* __restrict__ Wq, const float* __restrict__ Wk, const float* __restrict__ Wv,
    const float* __restrict__ bq, const float* __restrict__ bk, const float* __restrict__ bv,
    const int* __restrict__ pos,
    __bf16* __restrict__ Qh, __bf16* __restrict__ Kh, __bf16* __restrict__ Vt) {
  const int i0 = blockIdx.x << 6;
  const int jb = blockIdx.y;
  const int which = jb >> 3, h = jb & 7;
  const float* __restrict__ W    = (which == 0) ? Wq : (which == 1) ? Wk : Wv;
  const float* __restrict__ bias = (which == 0) ? bq : (which == 1) ? bk : bv;
  const int j0 = h << 6;

  __shared__ __bf16 As[64][72];
  __shared__ __bf16 Bs[64][72];

  const int tid = threadIdx.x;
  const int wv = tid >> 6, lane = tid & 63;
  const int l = lane & 15, seg = lane >> 4;
  const int sr = tid >> 2, sc = (tid & 3) << 4;

  f32x4 O[4];
#pragma unroll
  for (int nt = 0; nt < 4; ++nt) O[nt] = (f32x4){0.f, 0.f, 0.f, 0.f};

  for (int k0 = 0; k0 < 512; k0 += 64) {
    __syncthreads();
    const float* xp = X + (size_t)(i0 + sr) * 512 + k0 + sc;
    float4 x0 = *(const float4*)xp,       x1 = *(const float4*)(xp + 4),
           x2 = *(const float4*)(xp + 8), x3 = *(const float4*)(xp + 12);
    *(bf16x8*)&As[sr][sc]     = cvt2(x0, x1);
    *(bf16x8*)&As[sr][sc + 8] = cvt2(x2, x3);
    const float* wp = W + (size_t)(j0 + sr) * 512 + k0 + sc;
    float4 w0 = *(const float4*)wp,       w1 = *(const float4*)(wp + 4),
           w2 = *(const float4*)(wp + 8), w3 = *(const float4*)(wp + 12);
    *(bf16x8*)&Bs[sr][sc]     = cvt2(w0, w1);
    *(bf16x8*)&Bs[sr][sc + 8] = cvt2(w2, w3);
    __syncthreads();
    bf16x8 a0 = *(const bf16x8*)&As[wv * 16 + l][seg * 8];
    bf16x8 a1 = *(const bf16x8*)&As[wv * 16 + l][seg * 8 + 32];
#pragma unroll
    for (int nt = 0; nt < 4; ++nt) {
      bf16x8 b0 = *(const bf16x8*)&Bs[nt * 16 + l][seg * 8];
      bf16x8 b1 = *(const bf16x8*)&Bs[nt * 16 + l][seg * 8 + 32];
      O[nt] = __builtin_amdgcn_mfma_f32_16x16x32_bf16(a0, b0, O[nt], 0, 0, 0);
      O[nt] = __builtin_amdgcn_mfma_f32_16x16x32_bf16(a1, b1, O[nt], 0, 0, 0);
    }
  }

#pragma unroll
  for (int nt = 0; nt < 4; ++nt) {
    const float bb = bias[j0 + nt * 16 + l];
#pragma unroll
    for (int reg = 0; reg < 4; ++reg) O[nt][reg] += bb;
  }

  const int n = i0 >> 11, sb = i0 & 2047;
  const int nh = (n << 3) + h;

  __syncthreads();   // Bs becomes the epilogue bounce buffer

  if (which < 2) {
    const float qs  = (which == 0) ? 0.125f : 1.f;
    const float sgn = (which == 0) ? 1.f : -1.f;
    __bf16* __restrict__ Ob = (which == 0) ? Qh : Kh;
    float invf[4], l2sv[4];
#pragma unroll
    for (int nt = 0; nt < 4; ++nt) {
      const float kp = (float)((nt * 16 + l) >> 1);
      invf[nt] = exp2f(-0.41524100f * kp);
      l2sv[nt] = log2f((2.f * kp + 25.6f) * (1.f / 89.6f));
    }
#pragma unroll
    for (int reg = 0; reg < 4; ++reg) {
      const int sl = wv * 16 + seg * 4 + reg;
      const float p = (float)pos[n * S_LEN + sb + sl];
#pragma unroll
      for (int nt = 0; nt < 4; ++nt) {
        const float x  = O[nt][reg];
        const float xp = __shfl_xor(x, 1);
        const float ang = p * invf[nt];
        const float sn = sinf(ang), cn = cosf(ang);
        const float scl = exp2f(sgn * p * (1.f / 512.f) * l2sv[nt]) * qs;
        const int d = nt * 16 + l;
        const float o = (d & 1) ? (x * cn + xp * sn) : (x * cn - xp * sn);
        Bs[sl][d] = (__bf16)(o * scl);
      }
    }
    __syncthreads();
    __bf16* dst = Ob + (((size_t)nh * S_LEN + sb + sr) << 6) + sc;
    *(bf16x8*)dst       = *(bf16x8*)&Bs[sr][sc];
    *(bf16x8*)(dst + 8) = *(bf16x8*)&Bs[sr][sc + 8];
  } else {
#pragma unroll
    for (int reg = 0; reg < 4; ++reg) {
      const int sl = wv * 16 + seg * 4 + reg;
#pragma unroll
      for (int nt = 0; nt < 4; ++nt)
        Bs[sl][nt * 16 + l] = (__bf16)O[nt][reg];
    }
    __syncthreads();
    const int d = tid >> 2, part = tid & 3;
    __bf16 tmp[16];
#pragma unroll
    for (int i = 0; i < 16; ++i) tmp[i] = Bs[part * 16 + i][d];
    __bf16* dst = Vt + (((size_t)(nh * 64 + d)) << 11) + sb + part * 16;
    *(bf16x8*)dst       = *(bf16x8*)&tmp[0];
    *(bf16x8*)(dst + 8) = *(bf16x8*)&tmp[8];
  }
}

// ---------------------------------------------------------------------------
// Kernel 2: fused sigmoid-gated attention.  R5: back to 512 static blocks
// with heavy+light pairing (R4's 1024-block queue diluted the critical path:
// 4-way CU sharing slowed heavy blocks 146->230us).  Gate scan rewritten:
// 16-lane suffix products via DPP row_shl (VALU, identity=1.0 via old-value)
// instead of ds_bpermute chains; cross-lane broadcasts via 9 independent
// ds_swizzle ops (row-head 0x0010 / row-tail 0x01F0) under one waitcnt.
// ---------------------------------------------------------------------------
__global__ __launch_bounds__(256, 2) void attn_kernel(
    const __bf16* __restrict__ Qh, const __bf16* __restrict__ Kh,
    const __bf16* __restrict__ Vt, const float* __restrict__ imask,
    float* __restrict__ att) {
  const int id = blockIdx.x;
  const int nh = id >> 5;
  const int rbi = id & 31;
  const int rb = (id < 256) ? rbi : (31 - rbi);   // heavy+light pairing
  const int n = nh >> 3, h = nh & 7;
  const int tid = threadIdx.x;
  const int wv = tid >> 6, lane = tid & 63;
  const int l = lane & 15, seg = lane >> 4;

  __shared__ __bf16 Qs16[64][72];
  __shared__ __bf16 Ks16[64][72];
  __shared__ __bf16 Vt16[64][72];
  __shared__ __bf16 cs16[64][72];
  __shared__ float msk[64];

  for (int idx = tid; idx < 512; idx += 256) {
    int r = idx >> 3, c8 = (idx & 7) << 3;
    *(bf16x8*)&Qs16[r][c8] =
        *(const bf16x8*)(Qh + (((size_t)nh * S_LEN + rb * 64 + r) << 6) + c8);
  }

  f32x4 O[4];
  float pend[4][4];
  float Crow[4];
#pragma unroll
  for (int nt = 0; nt < 4; ++nt) O[nt] = (f32x4){0.f, 0.f, 0.f, 0.f};
#pragma unroll
  for (int r = 0; r < 4; ++r) {
    Crow[r] = 1.f;
#pragma unroll
    for (int nt = 0; nt < 4; ++nt) pend[r][nt] = 0.f;
  }

  for (int jt = rb; jt >= 0; --jt) {
    __syncthreads();
    for (int idx = tid; idx < 512; idx += 256) {
      int r = idx >> 3, c8 = (idx & 7) << 3;
      *(bf16x8*)&Ks16[r][c8] =
          *(const bf16x8*)(Kh + (((size_t)nh * S_LEN + jt * 64 + r) << 6) + c8);
      *(bf16x8*)&Vt16[r][c8] =
          *(const bf16x8*)(Vt + (((size_t)nh * 64 + r) << 11) + jt * 64 + c8);
    }
    if (tid < 64) msk[tid] = imask[n * S_LEN + jt * 64 + tid];
    __syncthreads();

    // ---- QK^T MFMAs ----
    bf16x8 aq0 = *(const bf16x8*)&Qs16[wv * 16 + l][seg * 8];
    bf16x8 aq1 = *(const bf16x8*)&Qs16[wv * 16 + l][seg * 8 + 32];
    f32x4 Sv[4];
#pragma unroll
    for (int nt = 0; nt < 4; ++nt) {
      bf16x8 bk0 = *(const bf16x8*)&Ks16[nt * 16 + l][seg * 8];
      bf16x8 bk1 = *(const bf16x8*)&Ks16[nt * 16 + l][seg * 8 + 32];
      f32x4 z = (f32x4){0.f, 0.f, 0.f, 0.f};
      z = __builtin_amdgcn_mfma_f32_16x16x32_bf16(aq0, bk0, z, 0, 0, 0);
      z = __builtin_amdgcn_mfma_f32_16x16x32_bf16(aq1, bk1, z, 0, 0, 0);
      Sv[nt] = z;
    }

    float v0f[4];
#pragma unroll
    for (int nt = 0; nt < 4; ++nt) v0f[nt] = (float)Vt16[nt * 16 + l][0];

    // ---- gate scan + coefficients, per query row ----
#pragma unroll
    for (int reg = 0; reg < 4; ++reg) {
      const int qrow = rb * 64 + wv * 16 + seg * 4 + reg;
      float a_[4], f_[4], p_[4];
#pragma unroll
      for (int nt = 0; nt < 4; ++nt) {
        const int key = jt * 64 + nt * 16 + l;
        const float s = Sv[nt][reg];
        const float mv = msk[nt * 16 + l];
        const float av = (key <= qrow)
            ? mv * __builtin_amdgcn_rcpf(1.f + __expf(-s))
            : 0.f;
        a_[nt] = av;
        f_[nt] = 1.f - av + EPS_G;
      }
      // 16-lane suffix products via DPP row_shl (OOB lanes contribute 1.0)
#pragma unroll
      for (int nt = 0; nt < 4; ++nt) {
        float p = f_[nt];
        p *= dpp_mov<ROW_SHL(1)>(p, 1.f);
        p *= dpp_mov<ROW_SHL(2)>(p, 1.f);
        p *= dpp_mov<ROW_SHL(4)>(p, 1.f);
        p *= dpp_mov<ROW_SHL(8)>(p, 1.f);
        p_[nt] = p;
      }
      // cross-lane broadcasts: 9 independent swizzles
      float P_[4], tl[4];
#pragma unroll
      for (int nt = 0; nt < 4; ++nt) {
        P_[nt] = swz_head(p_[nt]);   // bank total (suffix at row head)
        tl[nt] = swz_tail(f_[nt]);   // f at bank's last key
      }
      const float a0 = swz_head(a_[0]);
      const float T3 = 1.f, T2 = P_[3], T1 = T2 * P_[2], T0 = T1 * P_[1];
      const float Tarr[4] = {T0, T1, T2, T3};
      const float Ptile = T0 * P_[0];
      const float crow = Crow[reg];
#pragma unroll
      for (int nt = 0; nt < 4; ++nt) {
        const float pprev = dpp_mov<ROW_SHR(1)>(p_[nt], 0.f);  // p[l-1]
        float cv;
        if (l > 0)
          cv = a_[nt] * pprev * Tarr[nt] * crow;
        else if (nt > 0)
          cv = a_[nt] * tl[nt - 1] * P_[nt] * Tarr[nt] * crow;
        else
          cv = (jt == 0) ? a_[0] : 0.f;
        cs16[wv * 16 + seg * 4 + reg][nt * 16 + l] = (__bf16)cv;
      }
      const float f63 = tl[3];
      const float s0  = a0 * Ptile * crow;
      Crow[reg] = crow * Ptile;
#pragma unroll
      for (int nt = 0; nt < 4; ++nt) {
        O[nt][reg] += pend[reg][nt] * f63;
        pend[reg][nt] = s0 * v0f[nt];
      }
    }

    // ---- PV MFMAs ----
    bf16x8 ac0 = *(const bf16x8*)&cs16[wv * 16 + l][seg * 8];
    bf16x8 ac1 = *(const bf16x8*)&cs16[wv * 16 + l][seg * 8 + 32];
#pragma unroll
    for (int nt = 0; nt < 4; ++nt) {
      bf16x8 bv0 = *(const bf16x8*)&Vt16[nt * 16 + l][seg * 8];
      bf16x8 bv1 = *(const bf16x8*)&Vt16[nt * 16 + l][seg * 8 + 32];
      O[nt] = __builtin_amdgcn_mfma_f32_16x16x32_bf16(ac0, bv0, O[nt], 0, 0, 0);
      O[nt] = __builtin_amdgcn_mfma_f32_16x16x32_bf16(ac1, bv1, O[nt], 0, 0, 0);
    }
  }

  // epilogue: att[(n, s, h*64+d)] f32
#pragma unroll
  for (int nt = 0; nt < 4; ++nt)
#pragma unroll
    for (int reg = 0; reg < 4; ++reg) {
      const int srow = rb * 64 + wv * 16 + seg * 4 + reg;
      const int d = nt * 16 + l;
      att[((size_t)(n * S_LEN + srow)) * DMODEL + h * HDIM + d] = O[nt][reg];
    }
}

// ---------------------------------------------------------------------------
// Kernel 3: out = att @ Wo^T + bo  (bf16 MFMA)
// ---------------------------------------------------------------------------
__global__ __launch_bounds__(256) void out_gemm(const float* __restrict__ Xa,
                                                const float* __restrict__ Wo,
                                                const float* __restrict__ bo,
                                                float* __restrict__ Out) {
  const int i0 = blockIdx.x << 6, j0 = blockIdx.y << 6;
  __shared__ __bf16 As[64][72];
  __shared__ __bf16 Bs[64][72];

  const int tid = threadIdx.x;
  const int wv = tid >> 6, lane = tid & 63;
  const int l = lane & 15, seg = lane >> 4;
  const int sr = tid >> 2, sc = (tid & 3) << 4;

  f32x4 O[4];
#pragma unroll
  for (int nt = 0; nt < 4; ++nt) O[nt] = (f32x4){0.f, 0.f, 0.f, 0.f};

  for (int k0 = 0; k0 < 512; k0 += 64) {
    __syncthreads();
    const float* xp = Xa + (size_t)(i0 + sr) * 512 + k0 + sc;
    float4 x0 = *(const float4*)xp,       x1 = *(const float4*)(xp + 4),
           x2 = *(const float4*)(xp + 8), x3 = *(const float4*)(xp + 12);
    *(bf16x8*)&As[sr][sc]     = cvt2(x0, x1);
    *(bf16x8*)&As[sr][sc + 8] = cvt2(x2, x3);
    const float* wp = Wo + (size_t)(j0 + sr) * 512 + k0 + sc;
    float4 w0 = *(const float4*)wp,       w1 = *(const float4*)(wp + 4),
           w2 = *(const float4*)(wp + 8), w3 = *(const float4*)(wp + 12);
    *(bf16x8*)&Bs[sr][sc]     = cvt2(w0, w1);
    *(bf16x8*)&Bs[sr][sc + 8] = cvt2(w2, w3);
    __syncthreads();
    bf16x8 a0 = *(const bf16x8*)&As[wv * 16 + l][seg * 8];
    bf16x8 a1 = *(const bf16x8*)&As[wv * 16 + l][seg * 8 + 32];
#pragma unroll
    for (int nt = 0; nt < 4; ++nt) {
      bf16x8 b0 = *(const bf16x8*)&Bs[nt * 16 + l][seg * 8];
      bf16x8 b1 = *(const bf16x8*)&Bs[nt * 16 + l][seg * 8 + 32];
      O[nt] = __builtin_amdgcn_mfma_f32_16x16x32_bf16(a0, b0, O[nt], 0, 0, 0);
      O[nt] = __builtin_amdgcn_mfma_f32_16x16x32_bf16(a1, b1, O[nt], 0, 0, 0);
    }
  }

#pragma unroll
  for (int nt = 0; nt < 4; ++nt) {
    const float bb = bo[j0 + nt * 16 + l];
#pragma unroll
    for (int reg = 0; reg < 4; ++reg) {
      const int m = wv * 16 + seg * 4 + reg;
      Out[(size_t)(i0 + m) * 512 + j0 + nt * 16 + l] = O[nt][reg] + bb;
    }
  }
}

// ---------------------------------------------------------------------------
extern "C" void kernel_launch(void* const* d_in, const int* in_sizes, int n_in,
                              void* d_out, int out_size, void* d_ws, size_t ws_size,
                              hipStream_t stream) {
  (void)in_sizes; (void)n_in; (void)out_size; (void)ws_size;
  const float* seq  = (const float*)d_in[0];
  const float* mask = (const float*)d_in[1];
  const int*   pos  = (const int*)d_in[2];
  const float* Wq = (const float*)d_in[4];
  const float* bq = (const float*)d_in[5];
  const float* Wk = (const float*)d_in[6];
  const float* bk = (const float*)d_in[7];
  const float* Wv = (const float*)d_in[8];
  const float* bv = (const float*)d_in[9];
  const float* Wo = (const float*)d_in[10];
  const float* bo = (const float*)d_in[11];
  float* out = (float*)d_out;

  char* base = (char*)d_ws;
  float*  att = (float*)base;                     // 8 MB  (4096 x 512 f32)
  __bf16* Qh  = (__bf16*)(base + (8u  << 20));    // 4 MB  [nh][s][64]
  __bf16* Kh  = (__bf16*)(base + (12u << 20));    // 4 MB  [nh][s][64]
  __bf16* Vt  = (__bf16*)(base + (16u << 20));    // 4 MB  [nh][d][2048]

  qkv_gemm<<<dim3(64, 24), 256, 0, stream>>>(seq, Wq, Wk, Wv, bq, bk, bv, pos, Qh, Kh, Vt);
  attn_kernel<<<512, 256, 0, stream>>>(Qh, Kh, Vt, mask, att);
  out_gemm<<<dim3(64, 8), 256, 0, stream>>>(att, Wo, bo, out);
}

// Round 6
// 210.108 us; speedup vs baseline: 22.9709x; 1.0627x over previous
//
#include <hip/hip_runtime.h>
#include <math.h>

#define S_LEN 2048
#define DMODEL 512
#define HDIM 64
#define EPS_G 1e-8f

typedef __bf16 bf16x8 __attribute__((ext_vector_type(8)));
typedef float f32x4 __attribute__((ext_vector_type(4)));

__device__ __forceinline__ bf16x8 cvt2(const float4 a, const float4 b) {
  bf16x8 r;
  r[0] = (__bf16)a.x; r[1] = (__bf16)a.y; r[2] = (__bf16)a.z; r[3] = (__bf16)a.w;
  r[4] = (__bf16)b.x; r[5] = (__bf16)b.y; r[6] = (__bf16)b.z; r[7] = (__bf16)b.w;
  return r;
}

// DPP lane move within 16-lane rows; OOB lanes keep `oldv` (bound_ctrl=false).
template <int CTRL>
__device__ __forceinline__ float dpp_mov(float src, float oldv) {
  return __int_as_float(__builtin_amdgcn_update_dpp(
      __float_as_int(oldv), __float_as_int(src), CTRL, 0xF, 0xF, false));
}
#define ROW_SHL(n) (0x100 + (n))
#define ROW_SHR(n) (0x110 + (n))

__device__ __forceinline__ float swz_head(float v) {  // lane -> row head
  return __int_as_float(__builtin_amdgcn_ds_swizzle(__float_as_int(v), 0x0010));
}
__device__ __forceinline__ float swz_tail(float v) {  // lane -> row tail
  return __int_as_float(__builtin_amdgcn_ds_swizzle(__float_as_int(v), 0x01F0));
}

// ---------------------------------------------------------------------------
// Kernel 1: fused QKV projection, R6: ONE block computes Q,K,V for a
// (64-row, head) tile — X staged once for 24 MFMAs/k-iter (was 8 per 2-tile
// stage, X re-read 24x).  Epilogue: xpos->Qh/Kh bf16 [nh][s][64]; V -> bf16
// transposed [nh][d][s] via LDS bounce.
// ---------------------------------------------------------------------------
__global__ __launch_bounds__(256) void qkv_gemm(
    const float* __restrict__ X,
    const float* __restrict__ Wq, const float* __restrict__ Wk, const float* __restrict__ Wv,
    const float* __restrict__ bq, const float* __restrict__ bk, const float* __restrict__ bv,
    const int* __restrict__ pos,
    __bf16* __restrict__ Qh, __bf16* __restrict__ Kh, __bf16* __restrict__ Vt) {
  const int i0 = blockIdx.x << 6;
  const int h  = blockIdx.y;           // 0..7
  const int j0 = h << 6;
  const float* const Wsrc[3] = {Wq, Wk, Wv};

  __shared__ __bf16 Xs[64][72];
  __shared__ __bf16 Wls[3][64][72];

  const int tid = threadIdx.x;
  const int wv = tid >> 6, lane = tid & 63;
  const int l = lane & 15, seg = lane >> 4;
  const int sr = tid >> 2, sc = (tid & 3) << 4;

  f32x4 O[3][4];
#pragma unroll
  for (int w = 0; w < 3; ++w)
#pragma unroll
    for (int nt = 0; nt < 4; ++nt) O[w][nt] = (f32x4){0.f, 0.f, 0.f, 0.f};

  for (int k0 = 0; k0 < 512; k0 += 64) {
    __syncthreads();
    {
      const float* xp = X + (size_t)(i0 + sr) * 512 + k0 + sc;
      float4 x0 = *(const float4*)xp,       x1 = *(const float4*)(xp + 4),
             x2 = *(const float4*)(xp + 8), x3 = *(const float4*)(xp + 12);
      *(bf16x8*)&Xs[sr][sc]     = cvt2(x0, x1);
      *(bf16x8*)&Xs[sr][sc + 8] = cvt2(x2, x3);
    }
#pragma unroll
    for (int w = 0; w < 3; ++w) {
      const float* wp = Wsrc[w] + (size_t)(j0 + sr) * 512 + k0 + sc;
      float4 w0 = *(const float4*)wp,       w1 = *(const float4*)(wp + 4),
             w2 = *(const float4*)(wp + 8), w3 = *(const float4*)(wp + 12);
      *(bf16x8*)&Wls[w][sr][sc]     = cvt2(w0, w1);
      *(bf16x8*)&Wls[w][sr][sc + 8] = cvt2(w2, w3);
    }
    __syncthreads();
    bf16x8 a0 = *(const bf16x8*)&Xs[wv * 16 + l][seg * 8];
    bf16x8 a1 = *(const bf16x8*)&Xs[wv * 16 + l][seg * 8 + 32];
#pragma unroll
    for (int w = 0; w < 3; ++w)
#pragma unroll
      for (int nt = 0; nt < 4; ++nt) {
        bf16x8 b0 = *(const bf16x8*)&Wls[w][nt * 16 + l][seg * 8];
        bf16x8 b1 = *(const bf16x8*)&Wls[w][nt * 16 + l][seg * 8 + 32];
        O[w][nt] = __builtin_amdgcn_mfma_f32_16x16x32_bf16(a0, b0, O[w][nt], 0, 0, 0);
        O[w][nt] = __builtin_amdgcn_mfma_f32_16x16x32_bf16(a1, b1, O[w][nt], 0, 0, 0);
      }
  }

  // bias
  const float* const bsrc[3] = {bq, bk, bv};
#pragma unroll
  for (int w = 0; w < 3; ++w)
#pragma unroll
    for (int nt = 0; nt < 4; ++nt) {
      const float bb = bsrc[w][j0 + nt * 16 + l];
#pragma unroll
      for (int reg = 0; reg < 4; ++reg) O[w][nt][reg] += bb;
    }

  const int n = i0 >> 11, sb = i0 & 2047;
  const int nh = (n << 3) + h;
  const int sl = wv * 16 + seg * 4;    // +reg

  // xpos constants (depend on dim only)
  float invf[4], l2sv[4];
#pragma unroll
  for (int nt = 0; nt < 4; ++nt) {
    const float kp = (float)((nt * 16 + l) >> 1);
    invf[nt] = exp2f(-0.41524100f * kp);
    l2sv[nt] = log2f((2.f * kp + 25.6f) * (1.f / 89.6f));
  }
  float pv_[4];
#pragma unroll
  for (int reg = 0; reg < 4; ++reg)
    pv_[reg] = (float)pos[n * S_LEN + sb + sl + reg];

  __syncthreads();   // last MFMA reads done; Xs becomes epilogue bounce

  // ---- Q then K: xpos -> bounce -> coalesced store ----
#pragma unroll
  for (int w = 0; w < 2; ++w) {
    const float qs  = (w == 0) ? 0.125f : 1.f;
    const float sgn = (w == 0) ? 1.f : -1.f;
    __bf16* __restrict__ Ob = (w == 0) ? Qh : Kh;
#pragma unroll
    for (int reg = 0; reg < 4; ++reg) {
      const float p = pv_[reg];
#pragma unroll
      for (int nt = 0; nt < 4; ++nt) {
        const float x  = O[w][nt][reg];
        const float xp = __shfl_xor(x, 1);
        const float ang = p * invf[nt];
        const float sn = sinf(ang), cn = cosf(ang);
        const float scl = exp2f(sgn * p * (1.f / 512.f) * l2sv[nt]) * qs;
        const int d = nt * 16 + l;
        const float o = (d & 1) ? (x * cn + xp * sn) : (x * cn - xp * sn);
        Xs[sl + reg][d] = (__bf16)(o * scl);
      }
    }
    __syncthreads();
    __bf16* dst = Ob + (((size_t)nh * S_LEN + sb + sr) << 6) + sc;
    *(bf16x8*)dst       = *(bf16x8*)&Xs[sr][sc];
    *(bf16x8*)(dst + 8) = *(bf16x8*)&Xs[sr][sc + 8];
    __syncthreads();
  }

  // ---- V: bounce + transpose store ----
#pragma unroll
  for (int reg = 0; reg < 4; ++reg)
#pragma unroll
    for (int nt = 0; nt < 4; ++nt)
      Xs[sl + reg][nt * 16 + l] = (__bf16)O[2][nt][reg];
  __syncthreads();
  const int d = tid >> 2, part = tid & 3;
  __bf16 tmp[16];
#pragma unroll
  for (int i = 0; i < 16; ++i) tmp[i] = Xs[part * 16 + i][d];
  __bf16* dst = Vt + (((size_t)(nh * 64 + d)) << 11) + sb + part * 16;
  *(bf16x8*)dst       = *(bf16x8*)&tmp[0];
  *(bf16x8*)(dst + 8) = *(bf16x8*)&tmp[8];
}

// ---------------------------------------------------------------------------
// Kernel 2: fused sigmoid-gated attention.  R6: register-prefetch
// double-buffering — tile jt-1's K/V are global-loaded into registers right
// after tile jt's LDS stores, so HBM/L2 latency overlaps the tile's
// MFMA+scan compute instead of serializing at the barrier.
// ---------------------------------------------------------------------------
__global__ __launch_bounds__(256, 2) void attn_kernel(
    const __bf16* __restrict__ Qh, const __bf16* __restrict__ Kh,
    const __bf16* __restrict__ Vt, const float* __restrict__ imask,
    float* __restrict__ att) {
  const int id = blockIdx.x;
  const int nh = id >> 5;
  const int rbi = id & 31;
  const int rb = (id < 256) ? rbi : (31 - rbi);   // heavy+light pairing
  const int n = nh >> 3, h = nh & 7;
  const int tid = threadIdx.x;
  const int wv = tid >> 6, lane = tid & 63;
  const int l = lane & 15, seg = lane >> 4;
  const int pr = tid >> 3, pc = (tid & 7) << 3;   // staging row/col

  __shared__ __bf16 Qs16[64][72];
  __shared__ __bf16 Ks16[64][72];
  __shared__ __bf16 Vt16[64][72];
  __shared__ __bf16 cs16[64][72];
  __shared__ float msk[64];

  for (int idx = tid; idx < 512; idx += 256) {
    int r = idx >> 3, c8 = (idx & 7) << 3;
    *(bf16x8*)&Qs16[r][c8] =
        *(const bf16x8*)(Qh + (((size_t)nh * S_LEN + rb * 64 + r) << 6) + c8);
  }

  f32x4 O[4];
  float pend[4][4];
  float Crow[4];
#pragma unroll
  for (int nt = 0; nt < 4; ++nt) O[nt] = (f32x4){0.f, 0.f, 0.f, 0.f};
#pragma unroll
  for (int r = 0; r < 4; ++r) {
    Crow[r] = 1.f;
#pragma unroll
    for (int nt = 0; nt < 4; ++nt) pend[r][nt] = 0.f;
  }

  bf16x8 kp0, kp1, vp0, vp1;
  float mp = 0.f;
#define LOADKV(JT)                                                                     \
  kp0 = *(const bf16x8*)(Kh + (((size_t)nh * S_LEN + (JT) * 64 + pr) << 6) + pc);      \
  kp1 = *(const bf16x8*)(Kh + (((size_t)nh * S_LEN + (JT) * 64 + 32 + pr) << 6) + pc); \
  vp0 = *(const bf16x8*)(Vt + (((size_t)(nh * 64 + pr)) << 11) + (JT) * 64 + pc);      \
  vp1 = *(const bf16x8*)(Vt + (((size_t)(nh * 64 + 32 + pr)) << 11) + (JT) * 64 + pc); \
  if (tid < 64) mp = imask[n * S_LEN + (JT) * 64 + tid];

  LOADKV(rb)

  for (int jt = rb; jt >= 0; --jt) {
    __syncthreads();                       // previous tile's LDS reads done
    *(bf16x8*)&Ks16[pr][pc]      = kp0;
    *(bf16x8*)&Ks16[32 + pr][pc] = kp1;
    *(bf16x8*)&Vt16[pr][pc]      = vp0;
    *(bf16x8*)&Vt16[32 + pr][pc] = vp1;
    if (tid < 64) msk[tid] = mp;
    __syncthreads();
    if (jt > 0) { LOADKV(jt - 1) }         // prefetch overlaps compute below

    // ---- QK^T MFMAs ----
    bf16x8 aq0 = *(const bf16x8*)&Qs16[wv * 16 + l][seg * 8];
    bf16x8 aq1 = *(const bf16x8*)&Qs16[wv * 16 + l][seg * 8 + 32];
    f32x4 Sv[4];
#pragma unroll
    for (int nt = 0; nt < 4; ++nt) {
      bf16x8 bk0 = *(const bf16x8*)&Ks16[nt * 16 + l][seg * 8];
      bf16x8 bk1 = *(const bf16x8*)&Ks16[nt * 16 + l][seg * 8 + 32];
      f32x4 z = (f32x4){0.f, 0.f, 0.f, 0.f};
      z = __builtin_amdgcn_mfma_f32_16x16x32_bf16(aq0, bk0, z, 0, 0, 0);
      z = __builtin_amdgcn_mfma_f32_16x16x32_bf16(aq1, bk1, z, 0, 0, 0);
      Sv[nt] = z;
    }

    float v0f[4];
#pragma unroll
    for (int nt = 0; nt < 4; ++nt) v0f[nt] = (float)Vt16[nt * 16 + l][0];

    // ---- gate scan + coefficients, per query row ----
#pragma unroll
    for (int reg = 0; reg < 4; ++reg) {
      const int qrow = rb * 64 + wv * 16 + seg * 4 + reg;
      float a_[4], f_[4], p_[4];
#pragma unroll
      for (int nt = 0; nt < 4; ++nt) {
        const int key = jt * 64 + nt * 16 + l;
        const float s = Sv[nt][reg];
        const float mv = msk[nt * 16 + l];
        const float av = (key <= qrow)
            ? mv * __builtin_amdgcn_rcpf(1.f + __expf(-s))
            : 0.f;
        a_[nt] = av;
        f_[nt] = 1.f - av + EPS_G;
      }
#pragma unroll
      for (int nt = 0; nt < 4; ++nt) {
        float p = f_[nt];
        p *= dpp_mov<ROW_SHL(1)>(p, 1.f);
        p *= dpp_mov<ROW_SHL(2)>(p, 1.f);
        p *= dpp_mov<ROW_SHL(4)>(p, 1.f);
        p *= dpp_mov<ROW_SHL(8)>(p, 1.f);
        p_[nt] = p;
      }
      float P_[4], tl[4];
#pragma unroll
      for (int nt = 0; nt < 4; ++nt) {
        P_[nt] = swz_head(p_[nt]);
        tl[nt] = swz_tail(f_[nt]);
      }
      const float a0 = swz_head(a_[0]);
      const float T3 = 1.f, T2 = P_[3], T1 = T2 * P_[2], T0 = T1 * P_[1];
      const float Tarr[4] = {T0, T1, T2, T3};
      const float Ptile = T0 * P_[0];
      const float crow = Crow[reg];
#pragma unroll
      for (int nt = 0; nt < 4; ++nt) {
        const float pprev = dpp_mov<ROW_SHR(1)>(p_[nt], 0.f);
        float cv;
        if (l > 0)
          cv = a_[nt] * pprev * Tarr[nt] * crow;
        else if (nt > 0)
          cv = a_[nt] * tl[nt - 1] * P_[nt] * Tarr[nt] * crow;
        else
          cv = (jt == 0) ? a_[0] : 0.f;
        cs16[wv * 16 + seg * 4 + reg][nt * 16 + l] = (__bf16)cv;
      }
      const float f63 = tl[3];
      const float s0  = a0 * Ptile * crow;
      Crow[reg] = crow * Ptile;
#pragma unroll
      for (int nt = 0; nt < 4; ++nt) {
        O[nt][reg] += pend[reg][nt] * f63;
        pend[reg][nt] = s0 * v0f[nt];
      }
    }

    // ---- PV MFMAs ----
    bf16x8 ac0 = *(const bf16x8*)&cs16[wv * 16 + l][seg * 8];
    bf16x8 ac1 = *(const bf16x8*)&cs16[wv * 16 + l][seg * 8 + 32];
#pragma unroll
    for (int nt = 0; nt < 4; ++nt) {
      bf16x8 bv0 = *(const bf16x8*)&Vt16[nt * 16 + l][seg * 8];
      bf16x8 bv1 = *(const bf16x8*)&Vt16[nt * 16 + l][seg * 8 + 32];
      O[nt] = __builtin_amdgcn_mfma_f32_16x16x32_bf16(ac0, bv0, O[nt], 0, 0, 0);
      O[nt] = __builtin_amdgcn_mfma_f32_16x16x32_bf16(ac1, bv1, O[nt], 0, 0, 0);
    }
  }

  // epilogue: att[(n, s, h*64+d)] f32
#pragma unroll
  for (int nt = 0; nt < 4; ++nt)
#pragma unroll
    for (int reg = 0; reg < 4; ++reg) {
      const int srow = rb * 64 + wv * 16 + seg * 4 + reg;
      const int d = nt * 16 + l;
      att[((size_t)(n * S_LEN + srow)) * DMODEL + h * HDIM + d] = O[nt][reg];
    }
}

// ---------------------------------------------------------------------------
// Kernel 3: out = att @ Wo^T + bo.  R6: 64x128 tile (halves att re-reads,
// 16 MFMAs per stage per wave).
// ---------------------------------------------------------------------------
__global__ __launch_bounds__(256) void out_gemm(const float* __restrict__ Xa,
                                                const float* __restrict__ Wo,
                                                const float* __restrict__ bo,
                                                float* __restrict__ Out) {
  const int i0 = blockIdx.x << 6, j0 = blockIdx.y << 7;
  __shared__ __bf16 As[64][72];
  __shared__ __bf16 Bs[128][72];

  const int tid = threadIdx.x;
  const int wv = tid >> 6, lane = tid & 63;
  const int l = lane & 15, seg = lane >> 4;
  const int sr = tid >> 2, sc = (tid & 3) << 4;

  f32x4 O[8];
#pragma unroll
  for (int nt = 0; nt < 8; ++nt) O[nt] = (f32x4){0.f, 0.f, 0.f, 0.f};

  for (int k0 = 0; k0 < 512; k0 += 64) {
    __syncthreads();
    {
      const float* xp = Xa + (size_t)(i0 + sr) * 512 + k0 + sc;
      float4 x0 = *(const float4*)xp,       x1 = *(const float4*)(xp + 4),
             x2 = *(const float4*)(xp + 8), x3 = *(const float4*)(xp + 12);
      *(bf16x8*)&As[sr][sc]     = cvt2(x0, x1);
      *(bf16x8*)&As[sr][sc + 8] = cvt2(x2, x3);
    }
#pragma unroll
    for (int ps = 0; ps < 2; ++ps) {
      const int r = ps * 64 + sr;
      const float* wp = Wo + (size_t)(j0 + r) * 512 + k0 + sc;
      float4 w0 = *(const float4*)wp,       w1 = *(const float4*)(wp + 4),
             w2 = *(const float4*)(wp + 8), w3 = *(const float4*)(wp + 12);
      *(bf16x8*)&Bs[r][sc]     = cvt2(w0, w1);
      *(bf16x8*)&Bs[r][sc + 8] = cvt2(w2, w3);
    }
    __syncthreads();
    bf16x8 a0 = *(const bf16x8*)&As[wv * 16 + l][seg * 8];
    bf16x8 a1 = *(const bf16x8*)&As[wv * 16 + l][seg * 8 + 32];
#pragma unroll
    for (int nt = 0; nt < 8; ++nt) {
      bf16x8 b0 = *(const bf16x8*)&Bs[nt * 16 + l][seg * 8];
      bf16x8 b1 = *(const bf16x8*)&Bs[nt * 16 + l][seg * 8 + 32];
      O[nt] = __builtin_amdgcn_mfma_f32_16x16x32_bf16(a0, b0, O[nt], 0, 0, 0);
      O[nt] = __builtin_amdgcn_mfma_f32_16x16x32_bf16(a1, b1, O[nt], 0, 0, 0);
    }
  }

#pragma unroll
  for (int nt = 0; nt < 8; ++nt) {
    const float bb = bo[j0 + nt * 16 + l];
#pragma unroll
    for (int reg = 0; reg < 4; ++reg) {
      const int m = wv * 16 + seg * 4 + reg;
      Out[(size_t)(i0 + m) * 512 + j0 + nt * 16 + l] = O[nt][reg] + bb;
    }
  }
}

// ---------------------------------------------------------------------------
extern "C" void kernel_launch(void* const* d_in, const int* in_sizes, int n_in,
                              void* d_out, int out_size, void* d_ws, size_t ws_size,
                              hipStream_t stream) {
  (void)in_sizes; (void)n_in; (void)out_size; (void)ws_size;
  const float* seq  = (const float*)d_in[0];
  const float* mask = (const float*)d_in[1];
  const int*   pos  = (const int*)d_in[2];
  const float* Wq = (const float*)d_in[4];
  const float* bq = (const float*)d_in[5];
  const float* Wk = (const float*)d_in[6];
  const float* bk = (const float*)d_in[7];
  const float* Wv = (const float*)d_in[8];
  const float* bv = (const float*)d_in[9];
  const float* Wo = (const float*)d_in[10];
  const float* bo = (const float*)d_in[11];
  float* out = (float*)d_out;

  char* base = (char*)d_ws;
  float*  att = (float*)base;                     // 8 MB  (4096 x 512 f32)
  __bf16* Qh  = (__bf16*)(base + (8u  << 20));    // 4 MB  [nh][s][64]
  __bf16* Kh  = (__bf16*)(base + (12u << 20));    // 4 MB  [nh][s][64]
  __bf16* Vt  = (__bf16*)(base + (16u << 20));    // 4 MB  [nh][d][2048]

  qkv_gemm<<<dim3(64, 8), 256, 0, stream>>>(seq, Wq, Wk, Wv, bq, bk, bv, pos, Qh, Kh, Vt);
  attn_kernel<<<512, 256, 0, stream>>>(Qh, Kh, Vt, mask, att);
  out_gemm<<<dim3(64, 4), 256, 0, stream>>>(att, Wo, bo, out);
}

// Round 7
// 200.404 us; speedup vs baseline: 24.0832x; 1.0484x over previous
//
#include <hip/hip_runtime.h>
#include <math.h>

#define S_LEN 2048
#define DMODEL 512
#define HDIM 64
#define EPS_G 1e-8f

typedef __bf16 bf16x8 __attribute__((ext_vector_type(8)));
typedef __bf16 bf16x4 __attribute__((ext_vector_type(4)));
typedef float f32x4 __attribute__((ext_vector_type(4)));

__device__ __forceinline__ bf16x8 cvt2(const float4 a, const float4 b) {
  bf16x8 r;
  r[0] = (__bf16)a.x; r[1] = (__bf16)a.y; r[2] = (__bf16)a.z; r[3] = (__bf16)a.w;
  r[4] = (__bf16)b.x; r[5] = (__bf16)b.y; r[6] = (__bf16)b.z; r[7] = (__bf16)b.w;
  return r;
}

// DPP lane move within 16-lane rows; OOB lanes keep `oldv` (bound_ctrl=false).
template <int CTRL>
__device__ __forceinline__ float dpp_mov(float src, float oldv) {
  return __int_as_float(__builtin_amdgcn_update_dpp(
      __float_as_int(oldv), __float_as_int(src), CTRL, 0xF, 0xF, false));
}
#define ROW_SHL(n) (0x100 + (n))
#define ROW_SHR(n) (0x110 + (n))

__device__ __forceinline__ float swz_head(float v) {  // lane -> row head
  return __int_as_float(__builtin_amdgcn_ds_swizzle(__float_as_int(v), 0x0010));
}
__device__ __forceinline__ float swz_tail(float v) {  // lane -> row tail
  return __int_as_float(__builtin_amdgcn_ds_swizzle(__float_as_int(v), 0x01F0));
}

// ---------------------------------------------------------------------------
// Kernel 0: one-shot f32->bf16 conversion of X, Wq|Wk|Wv (stacked), Wo.
// R7 rationale: R6's GEMMs staged f32 + converted in-loop: 256 MB of f32
// staging traffic and ~72 VALU cvts per thread per k-iter dominated both
// GEMMs (~120us combined for 8.6 GFLOP).  Converting once makes the GEMM
// staging pure bf16x8 loads (W working set 1.5 MB -> L2-resident re-reads).
// ---------------------------------------------------------------------------
__global__ __launch_bounds__(256) void cvt_kernel(
    const float* __restrict__ X, const float* __restrict__ Wq,
    const float* __restrict__ Wk, const float* __restrict__ Wv,
    const float* __restrict__ Wo,
    __bf16* __restrict__ Xb, __bf16* __restrict__ Wb, __bf16* __restrict__ Wob) {
  const int u = blockIdx.x * 256 + threadIdx.x;   // float4 unit, 786432 total
  const float* src; __bf16* dst; int off;
  if (u < 524288)      { src = X;  dst = Xb;          off = u; }
  else if (u < 589824) { src = Wq; dst = Wb;          off = u - 524288; }
  else if (u < 655360) { src = Wk; dst = Wb + 262144; off = u - 589824; }
  else if (u < 720896) { src = Wv; dst = Wb + 524288; off = u - 655360; }
  else                 { src = Wo; dst = Wob;         off = u - 720896; }
  const float4 v = *(const float4*)(src + (size_t)off * 4);
  bf16x4 o;
  o[0] = (__bf16)v.x; o[1] = (__bf16)v.y; o[2] = (__bf16)v.z; o[3] = (__bf16)v.w;
  *(bf16x4*)(dst + (size_t)off * 4) = o;
}

// ---------------------------------------------------------------------------
// Kernel 1: fused QKV projection (all-bf16 staging).  One block = (64 rows,
// head): X staged once for 24 MFMAs/k-iter.  Epilogue: xpos -> Qh/Kh bf16
// [nh][s][64]; V -> bf16 transposed [nh][d][s] via LDS bounce.
// ---------------------------------------------------------------------------
__global__ __launch_bounds__(256) void qkv_gemm(
    const __bf16* __restrict__ Xb, const __bf16* __restrict__ Wb,
    const float* __restrict__ bq, const float* __restrict__ bk, const float* __restrict__ bv,
    const int* __restrict__ pos,
    __bf16* __restrict__ Qh, __bf16* __restrict__ Kh, __bf16* __restrict__ Vt) {
  const int i0 = blockIdx.x << 6;
  const int h  = blockIdx.y;           // 0..7
  const int j0 = h << 6;

  __shared__ __bf16 Xs[64][72];
  __shared__ __bf16 Wls[3][64][72];

  const int tid = threadIdx.x;
  const int wv = tid >> 6, lane = tid & 63;
  const int l = lane & 15, seg = lane >> 4;
  const int sr = tid >> 2, sc = (tid & 3) << 4;

  f32x4 O[3][4];
#pragma unroll
  for (int w = 0; w < 3; ++w)
#pragma unroll
    for (int nt = 0; nt < 4; ++nt) O[w][nt] = (f32x4){0.f, 0.f, 0.f, 0.f};

  for (int k0 = 0; k0 < 512; k0 += 64) {
    __syncthreads();
    {
      const __bf16* xp = Xb + (size_t)(i0 + sr) * 512 + k0 + sc;
      *(bf16x8*)&Xs[sr][sc]     = *(const bf16x8*)xp;
      *(bf16x8*)&Xs[sr][sc + 8] = *(const bf16x8*)(xp + 8);
    }
#pragma unroll
    for (int w = 0; w < 3; ++w) {
      const __bf16* wp = Wb + (size_t)w * 262144 + (size_t)(j0 + sr) * 512 + k0 + sc;
      *(bf16x8*)&Wls[w][sr][sc]     = *(const bf16x8*)wp;
      *(bf16x8*)&Wls[w][sr][sc + 8] = *(const bf16x8*)(wp + 8);
    }
    __syncthreads();
    bf16x8 a0 = *(const bf16x8*)&Xs[wv * 16 + l][seg * 8];
    bf16x8 a1 = *(const bf16x8*)&Xs[wv * 16 + l][seg * 8 + 32];
#pragma unroll
    for (int w = 0; w < 3; ++w)
#pragma unroll
      for (int nt = 0; nt < 4; ++nt) {
        bf16x8 b0 = *(const bf16x8*)&Wls[w][nt * 16 + l][seg * 8];
        bf16x8 b1 = *(const bf16x8*)&Wls[w][nt * 16 + l][seg * 8 + 32];
        O[w][nt] = __builtin_amdgcn_mfma_f32_16x16x32_bf16(a0, b0, O[w][nt], 0, 0, 0);
        O[w][nt] = __builtin_amdgcn_mfma_f32_16x16x32_bf16(a1, b1, O[w][nt], 0, 0, 0);
      }
  }

  const float* const bsrc[3] = {bq, bk, bv};
#pragma unroll
  for (int w = 0; w < 3; ++w)
#pragma unroll
    for (int nt = 0; nt < 4; ++nt) {
      const float bb = bsrc[w][j0 + nt * 16 + l];
#pragma unroll
      for (int reg = 0; reg < 4; ++reg) O[w][nt][reg] += bb;
    }

  const int n = i0 >> 11, sb = i0 & 2047;
  const int nh = (n << 3) + h;
  const int sl = wv * 16 + seg * 4;    // +reg

  float invf[4], l2sv[4];
#pragma unroll
  for (int nt = 0; nt < 4; ++nt) {
    const float kp = (float)((nt * 16 + l) >> 1);
    invf[nt] = exp2f(-0.41524100f * kp);
    l2sv[nt] = log2f((2.f * kp + 25.6f) * (1.f / 89.6f));
  }
  float pv_[4];
#pragma unroll
  for (int reg = 0; reg < 4; ++reg)
    pv_[reg] = (float)pos[n * S_LEN + sb + sl + reg];

  __syncthreads();   // last MFMA reads done; Xs becomes epilogue bounce

  // ---- Q then K: xpos -> bounce -> coalesced store ----
#pragma unroll
  for (int w = 0; w < 2; ++w) {
    const float qs  = (w == 0) ? 0.125f : 1.f;
    const float sgn = (w == 0) ? 1.f : -1.f;
    __bf16* __restrict__ Ob = (w == 0) ? Qh : Kh;
#pragma unroll
    for (int reg = 0; reg < 4; ++reg) {
      const float p = pv_[reg];
#pragma unroll
      for (int nt = 0; nt < 4; ++nt) {
        const float x  = O[w][nt][reg];
        const float xp = __shfl_xor(x, 1);
        const float ang = p * invf[nt];
        const float sn = sinf(ang), cn = cosf(ang);
        const float scl = exp2f(sgn * p * (1.f / 512.f) * l2sv[nt]) * qs;
        const int d = nt * 16 + l;
        const float o = (d & 1) ? (x * cn + xp * sn) : (x * cn - xp * sn);
        Xs[sl + reg][d] = (__bf16)(o * scl);
      }
    }
    __syncthreads();
    __bf16* dst = Ob + (((size_t)nh * S_LEN + sb + sr) << 6) + sc;
    *(bf16x8*)dst       = *(bf16x8*)&Xs[sr][sc];
    *(bf16x8*)(dst + 8) = *(bf16x8*)&Xs[sr][sc + 8];
    __syncthreads();
  }

  // ---- V: bounce + transpose store ----
#pragma unroll
  for (int reg = 0; reg < 4; ++reg)
#pragma unroll
    for (int nt = 0; nt < 4; ++nt)
      Xs[sl + reg][nt * 16 + l] = (__bf16)O[2][nt][reg];
  __syncthreads();
  const int d = tid >> 2, part = tid & 3;
  __bf16 tmp[16];
#pragma unroll
  for (int i = 0; i < 16; ++i) tmp[i] = Xs[part * 16 + i][d];
  __bf16* dst = Vt + (((size_t)(nh * 64 + d)) << 11) + sb + part * 16;
  *(bf16x8*)dst       = *(bf16x8*)&tmp[0];
  *(bf16x8*)(dst + 8) = *(bf16x8*)&tmp[8];
}

// ---------------------------------------------------------------------------
// Kernel 2: fused sigmoid-gated attention (R6 structure: register-prefetch
// double-buffering, DPP scan, static heavy+light pairing).  Unchanged in R7.
// ---------------------------------------------------------------------------
__global__ __launch_bounds__(256, 2) void attn_kernel(
    const __bf16* __restrict__ Qh, const __bf16* __restrict__ Kh,
    const __bf16* __restrict__ Vt, const float* __restrict__ imask,
    float* __restrict__ att) {
  const int id = blockIdx.x;
  const int nh = id >> 5;
  const int rbi = id & 31;
  const int rb = (id < 256) ? rbi : (31 - rbi);   // heavy+light pairing
  const int n = nh >> 3, h = nh & 7;
  const int tid = threadIdx.x;
  const int wv = tid >> 6, lane = tid & 63;
  const int l = lane & 15, seg = lane >> 4;
  const int pr = tid >> 3, pc = (tid & 7) << 3;   // staging row/col

  __shared__ __bf16 Qs16[64][72];
  __shared__ __bf16 Ks16[64][72];
  __shared__ __bf16 Vt16[64][72];
  __shared__ __bf16 cs16[64][72];
  __shared__ float msk[64];

  for (int idx = tid; idx < 512; idx += 256) {
    int r = idx >> 3, c8 = (idx & 7) << 3;
    *(bf16x8*)&Qs16[r][c8] =
        *(const bf16x8*)(Qh + (((size_t)nh * S_LEN + rb * 64 + r) << 6) + c8);
  }

  f32x4 O[4];
  float pend[4][4];
  float Crow[4];
#pragma unroll
  for (int nt = 0; nt < 4; ++nt) O[nt] = (f32x4){0.f, 0.f, 0.f, 0.f};
#pragma unroll
  for (int r = 0; r < 4; ++r) {
    Crow[r] = 1.f;
#pragma unroll
    for (int nt = 0; nt < 4; ++nt) pend[r][nt] = 0.f;
  }

  bf16x8 kp0, kp1, vp0, vp1;
  float mp = 0.f;
#define LOADKV(JT)                                                                     \
  kp0 = *(const bf16x8*)(Kh + (((size_t)nh * S_LEN + (JT) * 64 + pr) << 6) + pc);      \
  kp1 = *(const bf16x8*)(Kh + (((size_t)nh * S_LEN + (JT) * 64 + 32 + pr) << 6) + pc); \
  vp0 = *(const bf16x8*)(Vt + (((size_t)(nh * 64 + pr)) << 11) + (JT) * 64 + pc);      \
  vp1 = *(const bf16x8*)(Vt + (((size_t)(nh * 64 + 32 + pr)) << 11) + (JT) * 64 + pc); \
  if (tid < 64) mp = imask[n * S_LEN + (JT) * 64 + tid];

  LOADKV(rb)

  for (int jt = rb; jt >= 0; --jt) {
    __syncthreads();                       // previous tile's LDS reads done
    *(bf16x8*)&Ks16[pr][pc]      = kp0;
    *(bf16x8*)&Ks16[32 + pr][pc] = kp1;
    *(bf16x8*)&Vt16[pr][pc]      = vp0;
    *(bf16x8*)&Vt16[32 + pr][pc] = vp1;
    if (tid < 64) msk[tid] = mp;
    __syncthreads();
    if (jt > 0) { LOADKV(jt - 1) }         // prefetch overlaps compute below

    // ---- QK^T MFMAs ----
    bf16x8 aq0 = *(const bf16x8*)&Qs16[wv * 16 + l][seg * 8];
    bf16x8 aq1 = *(const bf16x8*)&Qs16[wv * 16 + l][seg * 8 + 32];
    f32x4 Sv[4];
#pragma unroll
    for (int nt = 0; nt < 4; ++nt) {
      bf16x8 bk0 = *(const bf16x8*)&Ks16[nt * 16 + l][seg * 8];
      bf16x8 bk1 = *(const bf16x8*)&Ks16[nt * 16 + l][seg * 8 + 32];
      f32x4 z = (f32x4){0.f, 0.f, 0.f, 0.f};
      z = __builtin_amdgcn_mfma_f32_16x16x32_bf16(aq0, bk0, z, 0, 0, 0);
      z = __builtin_amdgcn_mfma_f32_16x16x32_bf16(aq1, bk1, z, 0, 0, 0);
      Sv[nt] = z;
    }

    float v0f[4];
#pragma unroll
    for (int nt = 0; nt < 4; ++nt) v0f[nt] = (float)Vt16[nt * 16 + l][0];

    // ---- gate scan + coefficients, per query row ----
#pragma unroll
    for (int reg = 0; reg < 4; ++reg) {
      const int qrow = rb * 64 + wv * 16 + seg * 4 + reg;
      float a_[4], f_[4], p_[4];
#pragma unroll
      for (int nt = 0; nt < 4; ++nt) {
        const int key = jt * 64 + nt * 16 + l;
        const float s = Sv[nt][reg];
        const float mv = msk[nt * 16 + l];
        const float av = (key <= qrow)
            ? mv * __builtin_amdgcn_rcpf(1.f + __expf(-s))
            : 0.f;
        a_[nt] = av;
        f_[nt] = 1.f - av + EPS_G;
      }
#pragma unroll
      for (int nt = 0; nt < 4; ++nt) {
        float p = f_[nt];
        p *= dpp_mov<ROW_SHL(1)>(p, 1.f);
        p *= dpp_mov<ROW_SHL(2)>(p, 1.f);
        p *= dpp_mov<ROW_SHL(4)>(p, 1.f);
        p *= dpp_mov<ROW_SHL(8)>(p, 1.f);
        p_[nt] = p;
      }
      float P_[4], tl[4];
#pragma unroll
      for (int nt = 0; nt < 4; ++nt) {
        P_[nt] = swz_head(p_[nt]);
        tl[nt] = swz_tail(f_[nt]);
      }
      const float a0 = swz_head(a_[0]);
      const float T3 = 1.f, T2 = P_[3], T1 = T2 * P_[2], T0 = T1 * P_[1];
      const float Tarr[4] = {T0, T1, T2, T3};
      const float Ptile = T0 * P_[0];
      const float crow = Crow[reg];
#pragma unroll
      for (int nt = 0; nt < 4; ++nt) {
        const float pprev = dpp_mov<ROW_SHR(1)>(p_[nt], 0.f);
        float cv;
        if (l > 0)
          cv = a_[nt] * pprev * Tarr[nt] * crow;
        else if (nt > 0)
          cv = a_[nt] * tl[nt - 1] * P_[nt] * Tarr[nt] * crow;
        else
          cv = (jt == 0) ? a_[0] : 0.f;
        cs16[wv * 16 + seg * 4 + reg][nt * 16 + l] = (__bf16)cv;
      }
      const float f63 = tl[3];
      const float s0  = a0 * Ptile * crow;
      Crow[reg] = crow * Ptile;
#pragma unroll
      for (int nt = 0; nt < 4; ++nt) {
        O[nt][reg] += pend[reg][nt] * f63;
        pend[reg][nt] = s0 * v0f[nt];
      }
    }

    // ---- PV MFMAs ----
    bf16x8 ac0 = *(const bf16x8*)&cs16[wv * 16 + l][seg * 8];
    bf16x8 ac1 = *(const bf16x8*)&cs16[wv * 16 + l][seg * 8 + 32];
#pragma unroll
    for (int nt = 0; nt < 4; ++nt) {
      bf16x8 bv0 = *(const bf16x8*)&Vt16[nt * 16 + l][seg * 8];
      bf16x8 bv1 = *(const bf16x8*)&Vt16[nt * 16 + l][seg * 8 + 32];
      O[nt] = __builtin_amdgcn_mfma_f32_16x16x32_bf16(ac0, bv0, O[nt], 0, 0, 0);
      O[nt] = __builtin_amdgcn_mfma_f32_16x16x32_bf16(ac1, bv1, O[nt], 0, 0, 0);
    }
  }

  // epilogue: att[(n, s, h*64+d)] f32
#pragma unroll
  for (int nt = 0; nt < 4; ++nt)
#pragma unroll
    for (int reg = 0; reg < 4; ++reg) {
      const int srow = rb * 64 + wv * 16 + seg * 4 + reg;
      const int d = nt * 16 + l;
      att[((size_t)(n * S_LEN + srow)) * DMODEL + h * HDIM + d] = O[nt][reg];
    }
}

// ---------------------------------------------------------------------------
// Kernel 3: out = att @ Wo^T + bo.  64x128 tile; att (f32) converted in
// staging, Wo staged as pre-converted bf16 (L2-resident re-reads).
// ---------------------------------------------------------------------------
__global__ __launch_bounds__(256) void out_gemm(const float* __restrict__ Xa,
                                                const __bf16* __restrict__ Wob,
                                                const float* __restrict__ bo,
                                                float* __restrict__ Out) {
  const int i0 = blockIdx.x << 6, j0 = blockIdx.y << 7;
  __shared__ __bf16 As[64][72];
  __shared__ __bf16 Bs[128][72];

  const int tid = threadIdx.x;
  const int wv = tid >> 6, lane = tid & 63;
  const int l = lane & 15, seg = lane >> 4;
  const int sr = tid >> 2, sc = (tid & 3) << 4;

  f32x4 O[8];
#pragma unroll
  for (int nt = 0; nt < 8; ++nt) O[nt] = (f32x4){0.f, 0.f, 0.f, 0.f};

  for (int k0 = 0; k0 < 512; k0 += 64) {
    __syncthreads();
    {
      const float* xp = Xa + (size_t)(i0 + sr) * 512 + k0 + sc;
      float4 x0 = *(const float4*)xp,       x1 = *(const float4*)(xp + 4),
             x2 = *(const float4*)(xp + 8), x3 = *(const float4*)(xp + 12);
      *(bf16x8*)&As[sr][sc]     = cvt2(x0, x1);
      *(bf16x8*)&As[sr][sc + 8] = cvt2(x2, x3);
    }
#pragma unroll
    for (int ps = 0; ps < 2; ++ps) {
      const int r = ps * 64 + sr;
      const __bf16* wp = Wob + (size_t)(j0 + r) * 512 + k0 + sc;
      *(bf16x8*)&Bs[r][sc]     = *(const bf16x8*)wp;
      *(bf16x8*)&Bs[r][sc + 8] = *(const bf16x8*)(wp + 8);
    }
    __syncthreads();
    bf16x8 a0 = *(const bf16x8*)&As[wv * 16 + l][seg * 8];
    bf16x8 a1 = *(const bf16x8*)&As[wv * 16 + l][seg * 8 + 32];
#pragma unroll
    for (int nt = 0; nt < 8; ++nt) {
      bf16x8 b0 = *(const bf16x8*)&Bs[nt * 16 + l][seg * 8];
      bf16x8 b1 = *(const bf16x8*)&Bs[nt * 16 + l][seg * 8 + 32];
      O[nt] = __builtin_amdgcn_mfma_f32_16x16x32_bf16(a0, b0, O[nt], 0, 0, 0);
      O[nt] = __builtin_amdgcn_mfma_f32_16x16x32_bf16(a1, b1, O[nt], 0, 0, 0);
    }
  }

#pragma unroll
  for (int nt = 0; nt < 8; ++nt) {
    const float bb = bo[j0 + nt * 16 + l];
#pragma unroll
    for (int reg = 0; reg < 4; ++reg) {
      const int m = wv * 16 + seg * 4 + reg;
      Out[(size_t)(i0 + m) * 512 + j0 + nt * 16 + l] = O[nt][reg] + bb;
    }
  }
}

// ---------------------------------------------------------------------------
extern "C" void kernel_launch(void* const* d_in, const int* in_sizes, int n_in,
                              void* d_out, int out_size, void* d_ws, size_t ws_size,
                              hipStream_t stream) {
  (void)in_sizes; (void)n_in; (void)out_size; (void)ws_size;
  const float* seq  = (const float*)d_in[0];
  const float* mask = (const float*)d_in[1];
  const int*   pos  = (const int*)d_in[2];
  const float* Wq = (const float*)d_in[4];
  const float* bq = (const float*)d_in[5];
  const float* Wk = (const float*)d_in[6];
  const float* bk = (const float*)d_in[7];
  const float* Wv = (const float*)d_in[8];
  const float* bv = (const float*)d_in[9];
  const float* Wo = (const float*)d_in[10];
  const float* bo = (const float*)d_in[11];
  float* out = (float*)d_out;

  char* base = (char*)d_ws;
  float*  att = (float*)base;                     // 8 MB   (4096 x 512 f32)
  __bf16* Qh  = (__bf16*)(base + (8u  << 20));    // 4 MB   [nh][s][64]
  __bf16* Kh  = (__bf16*)(base + (12u << 20));    // 4 MB   [nh][s][64]
  __bf16* Vt  = (__bf16*)(base + (16u << 20));    // 4 MB   [nh][d][2048]
  __bf16* Xb  = (__bf16*)(base + (20u << 20));    // 4 MB   (4096 x 512)
  __bf16* Wb  = (__bf16*)(base + (24u << 20));    // 1.5 MB (3 x 512 x 512)
  __bf16* Wob = (__bf16*)(base + (26u << 20));    // 0.5 MB (512 x 512)

  cvt_kernel<<<3072, 256, 0, stream>>>(seq, Wq, Wk, Wv, Wo, Xb, Wb, Wob);
  qkv_gemm<<<dim3(64, 8), 256, 0, stream>>>(Xb, Wb, bq, bk, bv, pos, Qh, Kh, Vt);
  attn_kernel<<<512, 256, 0, stream>>>(Qh, Kh, Vt, mask, att);
  out_gemm<<<dim3(64, 4), 256, 0, stream>>>(att, Wob, bo, out);
}

// Round 8
// 174.617 us; speedup vs baseline: 27.6397x; 1.1477x over previous
//
#include <hip/hip_runtime.h>
#include <math.h>

#define S_LEN 2048
#define DMODEL 512
#define HDIM 64
#define EPS_G 1e-8f

typedef __bf16 bf16x8 __attribute__((ext_vector_type(8)));
typedef __bf16 bf16x4 __attribute__((ext_vector_type(4)));
typedef float f32x4 __attribute__((ext_vector_type(4)));

// DPP lane move within 16-lane rows; OOB lanes keep `oldv` (bound_ctrl=false).
template <int CTRL>
__device__ __forceinline__ float dpp_mov(float src, float oldv) {
  return __int_as_float(__builtin_amdgcn_update_dpp(
      __float_as_int(oldv), __float_as_int(src), CTRL, 0xF, 0xF, false));
}
#define ROW_SHL(n) (0x100 + (n))
#define ROW_SHR(n) (0x110 + (n))

__device__ __forceinline__ float swz_head(float v) {  // lane -> row head
  return __int_as_float(__builtin_amdgcn_ds_swizzle(__float_as_int(v), 0x0010));
}
__device__ __forceinline__ float swz_tail(float v) {  // lane -> row tail
  return __int_as_float(__builtin_amdgcn_ds_swizzle(__float_as_int(v), 0x01F0));
}

// ---------------------------------------------------------------------------
// Kernel 0: one-shot f32->bf16 conversion of X, Wq|Wk|Wv (stacked), Wo.
// ---------------------------------------------------------------------------
__global__ __launch_bounds__(256) void cvt_kernel(
    const float* __restrict__ X, const float* __restrict__ Wq,
    const float* __restrict__ Wk, const float* __restrict__ Wv,
    const float* __restrict__ Wo,
    __bf16* __restrict__ Xb, __bf16* __restrict__ Wb, __bf16* __restrict__ Wob) {
  const int u = blockIdx.x * 256 + threadIdx.x;   // float4 unit, 786432 total
  const float* src; __bf16* dst; int off;
  if (u < 524288)      { src = X;  dst = Xb;          off = u; }
  else if (u < 589824) { src = Wq; dst = Wb;          off = u - 524288; }
  else if (u < 655360) { src = Wk; dst = Wb + 262144; off = u - 589824; }
  else if (u < 720896) { src = Wv; dst = Wb + 524288; off = u - 655360; }
  else                 { src = Wo; dst = Wob;         off = u - 720896; }
  const float4 v = *(const float4*)(src + (size_t)off * 4);
  bf16x4 o;
  o[0] = (__bf16)v.x; o[1] = (__bf16)v.y; o[2] = (__bf16)v.z; o[3] = (__bf16)v.w;
  *(bf16x4*)(dst + (size_t)off * 4) = o;
}

// ---------------------------------------------------------------------------
// Kernel 1: fused QKV projection (bf16 MFMA) with register-prefetch
// double-buffered K-loop (R6-proven pattern).  Epilogue: xpos -> Qh/Kh,
// V -> transposed Vt, all bf16.
// ---------------------------------------------------------------------------
__global__ __launch_bounds__(256, 2) void qkv_gemm(
    const __bf16* __restrict__ Xb, const __bf16* __restrict__ Wb,
    const float* __restrict__ bq, const float* __restrict__ bk, const float* __restrict__ bv,
    const int* __restrict__ pos,
    __bf16* __restrict__ Qh, __bf16* __restrict__ Kh, __bf16* __restrict__ Vt) {
  const int i0 = blockIdx.x << 6;
  const int h  = blockIdx.y;           // 0..7
  const int j0 = h << 6;

  __shared__ __bf16 Xs[64][72];
  __shared__ __bf16 Wls[3][64][72];

  const int tid = threadIdx.x;
  const int wv = tid >> 6, lane = tid & 63;
  const int l = lane & 15, seg = lane >> 4;
  const int sr = tid >> 2, sc = (tid & 3) << 4;

  f32x4 O[3][4];
#pragma unroll
  for (int w = 0; w < 3; ++w)
#pragma unroll
    for (int nt = 0; nt < 4; ++nt) O[w][nt] = (f32x4){0.f, 0.f, 0.f, 0.f};

  bf16x8 xr0, xr1, wr[3][2];
#define LOADQKV(K0)                                                                   \
  {                                                                                   \
    const __bf16* xp = Xb + (size_t)(i0 + sr) * 512 + (K0) + sc;                      \
    xr0 = *(const bf16x8*)xp; xr1 = *(const bf16x8*)(xp + 8);                         \
    _Pragma("unroll")                                                                 \
    for (int w = 0; w < 3; ++w) {                                                     \
      const __bf16* wp = Wb + (size_t)w * 262144 + (size_t)(j0 + sr) * 512 + (K0) + sc;\
      wr[w][0] = *(const bf16x8*)wp; wr[w][1] = *(const bf16x8*)(wp + 8);             \
    }                                                                                 \
  }

  LOADQKV(0)
  for (int k0 = 0; k0 < 512; k0 += 64) {
    __syncthreads();
    *(bf16x8*)&Xs[sr][sc]     = xr0;
    *(bf16x8*)&Xs[sr][sc + 8] = xr1;
#pragma unroll
    for (int w = 0; w < 3; ++w) {
      *(bf16x8*)&Wls[w][sr][sc]     = wr[w][0];
      *(bf16x8*)&Wls[w][sr][sc + 8] = wr[w][1];
    }
    __syncthreads();
    if (k0 < 448) LOADQKV(k0 + 64)

    bf16x8 a0 = *(const bf16x8*)&Xs[wv * 16 + l][seg * 8];
    bf16x8 a1 = *(const bf16x8*)&Xs[wv * 16 + l][seg * 8 + 32];
#pragma unroll
    for (int w = 0; w < 3; ++w)
#pragma unroll
      for (int nt = 0; nt < 4; ++nt) {
        bf16x8 b0 = *(const bf16x8*)&Wls[w][nt * 16 + l][seg * 8];
        bf16x8 b1 = *(const bf16x8*)&Wls[w][nt * 16 + l][seg * 8 + 32];
        O[w][nt] = __builtin_amdgcn_mfma_f32_16x16x32_bf16(a0, b0, O[w][nt], 0, 0, 0);
        O[w][nt] = __builtin_amdgcn_mfma_f32_16x16x32_bf16(a1, b1, O[w][nt], 0, 0, 0);
      }
  }

  const float* const bsrc[3] = {bq, bk, bv};
#pragma unroll
  for (int w = 0; w < 3; ++w)
#pragma unroll
    for (int nt = 0; nt < 4; ++nt) {
      const float bb = bsrc[w][j0 + nt * 16 + l];
#pragma unroll
      for (int reg = 0; reg < 4; ++reg) O[w][nt][reg] += bb;
    }

  const int n = i0 >> 11, sb = i0 & 2047;
  const int nh = (n << 3) + h;
  const int sl = wv * 16 + seg * 4;    // +reg

  float invf[4], l2sv[4];
#pragma unroll
  for (int nt = 0; nt < 4; ++nt) {
    const float kp = (float)((nt * 16 + l) >> 1);
    invf[nt] = exp2f(-0.41524100f * kp);
    l2sv[nt] = log2f((2.f * kp + 25.6f) * (1.f / 89.6f));
  }
  float pv_[4];
#pragma unroll
  for (int reg = 0; reg < 4; ++reg)
    pv_[reg] = (float)pos[n * S_LEN + sb + sl + reg];

  __syncthreads();   // last MFMA reads done; Xs becomes epilogue bounce

#pragma unroll
  for (int w = 0; w < 2; ++w) {
    const float qs  = (w == 0) ? 0.125f : 1.f;
    const float sgn = (w == 0) ? 1.f : -1.f;
    __bf16* __restrict__ Ob = (w == 0) ? Qh : Kh;
#pragma unroll
    for (int reg = 0; reg < 4; ++reg) {
      const float p = pv_[reg];
#pragma unroll
      for (int nt = 0; nt < 4; ++nt) {
        const float x  = O[w][nt][reg];
        const float xp = __shfl_xor(x, 1);
        const float ang = p * invf[nt];
        const float sn = sinf(ang), cn = cosf(ang);
        const float scl = exp2f(sgn * p * (1.f / 512.f) * l2sv[nt]) * qs;
        const int d = nt * 16 + l;
        const float o = (d & 1) ? (x * cn + xp * sn) : (x * cn - xp * sn);
        Xs[sl + reg][d] = (__bf16)(o * scl);
      }
    }
    __syncthreads();
    __bf16* dst = Ob + (((size_t)nh * S_LEN + sb + sr) << 6) + sc;
    *(bf16x8*)dst       = *(bf16x8*)&Xs[sr][sc];
    *(bf16x8*)(dst + 8) = *(bf16x8*)&Xs[sr][sc + 8];
    __syncthreads();
  }

#pragma unroll
  for (int reg = 0; reg < 4; ++reg)
#pragma unroll
    for (int nt = 0; nt < 4; ++nt)
      Xs[sl + reg][nt * 16 + l] = (__bf16)O[2][nt][reg];
  __syncthreads();
  const int d = tid >> 2, part = tid & 3;
  __bf16 tmp[16];
#pragma unroll
  for (int i = 0; i < 16; ++i) tmp[i] = Xs[part * 16 + i][d];
  __bf16* dst = Vt + (((size_t)(nh * 64 + d)) << 11) + sb + part * 16;
  *(bf16x8*)dst       = *(bf16x8*)&tmp[0];
  *(bf16x8*)(dst + 8) = *(bf16x8*)&tmp[8];
}

// ---------------------------------------------------------------------------
// Kernel 2: sigmoid-gated attention, SPLIT-K chunks (R8).
// R7 showed attn's 88us == the serial critical path of the rb=31 block
// (32 tiles x 6.6k cy; OccupancyPercent 12% == tail-dominated).  Each (nh,rb)
// is split into <=8-tile chunks (1280 blocks).  A chunk is self-contained:
// it resolves its own low-boundary pending term via a direct Q.K[m-1] dot
// (key m-1 is causal-past for the whole row block), and exports partial O
// (f32) + per-row product P.  The t=0 term (coefficient exactly a[0], no
// suffix factors) is exported unscaled as a0.  Single-chunk blocks (rb<8)
// write att (bf16) directly.
// ---------------------------------------------------------------------------
__global__ __launch_bounds__(256, 2) void attn_chunk(
    const __bf16* __restrict__ Qh, const __bf16* __restrict__ Kh,
    const __bf16* __restrict__ Vt, const float* __restrict__ imask,
    __bf16* __restrict__ att, float* __restrict__ PartO,
    float* __restrict__ PartP, float* __restrict__ PartA0) {
  const int id = blockIdx.x;
  const int nh = id & 15;
  const int t  = id >> 4;              // 0..79 chunk id within head
  int rb, c, nc;
  if (t < 8)       { rb = t; c = 0; nc = 1; }
  else if (t < 24) { int u = t - 8;  rb = 8  + (u >> 1); c = u & 1;     nc = 2; }
  else if (t < 48) { int u = t - 24; rb = 16 + u / 3;    c = u - 3 * (u / 3); nc = 3; }
  else             { int u = t - 48; rb = 24 + (u >> 2); c = u & 3;     nc = 4; }
  const int hi = rb - (c << 3);
  const int lo = (c == nc - 1) ? 0 : hi - 7;

  const int n = nh >> 3, h = nh & 7;
  const int tid = threadIdx.x;
  const int wv = tid >> 6, lane = tid & 63;
  const int l = lane & 15, seg = lane >> 4;
  const int pr = tid >> 3, pc = (tid & 7) << 3;

  __shared__ __bf16 Qs16[64][72];
  __shared__ __bf16 Ks16[64][72];
  __shared__ __bf16 Vt16[64][72];
  __shared__ __bf16 cs16[64][72];
  __shared__ float msk[64];

  for (int idx = tid; idx < 512; idx += 256) {
    int r = idx >> 3, c8 = (idx & 7) << 3;
    *(bf16x8*)&Qs16[r][c8] =
        *(const bf16x8*)(Qh + (((size_t)nh * S_LEN + rb * 64 + r) << 6) + c8);
  }

  f32x4 O[4];
  float pend[4][4];
  float Crow[4];
  float a0k0[4];                       // a at key 0 (lowest chunk only)
#pragma unroll
  for (int nt = 0; nt < 4; ++nt) O[nt] = (f32x4){0.f, 0.f, 0.f, 0.f};
#pragma unroll
  for (int r = 0; r < 4; ++r) {
    Crow[r] = 1.f; a0k0[r] = 0.f;
#pragma unroll
    for (int nt = 0; nt < 4; ++nt) pend[r][nt] = 0.f;
  }

  bf16x8 kp0, kp1, vp0, vp1;
  float mp = 0.f;
#define LOADKV(JT)                                                                     \
  kp0 = *(const bf16x8*)(Kh + (((size_t)nh * S_LEN + (JT) * 64 + pr) << 6) + pc);      \
  kp1 = *(const bf16x8*)(Kh + (((size_t)nh * S_LEN + (JT) * 64 + 32 + pr) << 6) + pc); \
  vp0 = *(const bf16x8*)(Vt + (((size_t)(nh * 64 + pr)) << 11) + (JT) * 64 + pc);      \
  vp1 = *(const bf16x8*)(Vt + (((size_t)(nh * 64 + 32 + pr)) << 11) + (JT) * 64 + pc); \
  if (tid < 64) mp = imask[n * S_LEN + (JT) * 64 + tid];

  LOADKV(hi)

  for (int jt = hi; jt >= lo; --jt) {
    __syncthreads();
    *(bf16x8*)&Ks16[pr][pc]      = kp0;
    *(bf16x8*)&Ks16[32 + pr][pc] = kp1;
    *(bf16x8*)&Vt16[pr][pc]      = vp0;
    *(bf16x8*)&Vt16[32 + pr][pc] = vp1;
    if (tid < 64) msk[tid] = mp;
    __syncthreads();
    if (jt > lo) { LOADKV(jt - 1) }

    // ---- QK^T MFMAs ----
    bf16x8 aq0 = *(const bf16x8*)&Qs16[wv * 16 + l][seg * 8];
    bf16x8 aq1 = *(const bf16x8*)&Qs16[wv * 16 + l][seg * 8 + 32];
    f32x4 Sv[4];
#pragma unroll
    for (int nt = 0; nt < 4; ++nt) {
      bf16x8 bk0 = *(const bf16x8*)&Ks16[nt * 16 + l][seg * 8];
      bf16x8 bk1 = *(const bf16x8*)&Ks16[nt * 16 + l][seg * 8 + 32];
      f32x4 z = (f32x4){0.f, 0.f, 0.f, 0.f};
      z = __builtin_amdgcn_mfma_f32_16x16x32_bf16(aq0, bk0, z, 0, 0, 0);
      z = __builtin_amdgcn_mfma_f32_16x16x32_bf16(aq1, bk1, z, 0, 0, 0);
      Sv[nt] = z;
    }

    float v0f[4];
#pragma unroll
    for (int nt = 0; nt < 4; ++nt) v0f[nt] = (float)Vt16[nt * 16 + l][0];

    // ---- gate scan + coefficients, per query row ----
#pragma unroll
    for (int reg = 0; reg < 4; ++reg) {
      const int qrow = rb * 64 + wv * 16 + seg * 4 + reg;
      float a_[4], f_[4], p_[4];
#pragma unroll
      for (int nt = 0; nt < 4; ++nt) {
        const int key = jt * 64 + nt * 16 + l;
        const float s = Sv[nt][reg];
        const float mv = msk[nt * 16 + l];
        const float av = (key <= qrow)
            ? mv * __builtin_amdgcn_rcpf(1.f + __expf(-s))
            : 0.f;
        a_[nt] = av;
        f_[nt] = 1.f - av + EPS_G;
      }
#pragma unroll
      for (int nt = 0; nt < 4; ++nt) {
        float p = f_[nt];
        p *= dpp_mov<ROW_SHL(1)>(p, 1.f);
        p *= dpp_mov<ROW_SHL(2)>(p, 1.f);
        p *= dpp_mov<ROW_SHL(4)>(p, 1.f);
        p *= dpp_mov<ROW_SHL(8)>(p, 1.f);
        p_[nt] = p;
      }
      float P_[4], tl[4];
#pragma unroll
      for (int nt = 0; nt < 4; ++nt) {
        P_[nt] = swz_head(p_[nt]);
        tl[nt] = swz_tail(f_[nt]);
      }
      const float a0 = swz_head(a_[0]);
      const float T3 = 1.f, T2 = P_[3], T1 = T2 * P_[2], T0 = T1 * P_[1];
      const float Tarr[4] = {T0, T1, T2, T3};
      const float Ptile = T0 * P_[0];
      const float crow = Crow[reg];
#pragma unroll
      for (int nt = 0; nt < 4; ++nt) {
        const float pprev = dpp_mov<ROW_SHR(1)>(p_[nt], 0.f);
        float cv;
        if (l > 0)
          cv = a_[nt] * pprev * Tarr[nt] * crow;
        else if (nt > 0)
          cv = a_[nt] * tl[nt - 1] * P_[nt] * Tarr[nt] * crow;
        else
          cv = (jt == 0 && nc == 1) ? a_[0] : 0.f;  // t=0 direct only if unsplit
        cs16[wv * 16 + seg * 4 + reg][nt * 16 + l] = (__bf16)cv;
      }
      if (jt == 0) a0k0[reg] = a0;      // export a[key 0] for combine (nc>1)
      const float f63 = tl[3];
      const float s0  = a0 * Ptile * crow;
      Crow[reg] = crow * Ptile;
#pragma unroll
      for (int nt = 0; nt < 4; ++nt) {
        O[nt][reg] += pend[reg][nt] * f63;
        pend[reg][nt] = s0 * v0f[nt];
      }
    }

    // ---- PV MFMAs ----
    bf16x8 ac0 = *(const bf16x8*)&cs16[wv * 16 + l][seg * 8];
    bf16x8 ac1 = *(const bf16x8*)&cs16[wv * 16 + l][seg * 8 + 32];
#pragma unroll
    for (int nt = 0; nt < 4; ++nt) {
      bf16x8 bv0 = *(const bf16x8*)&Vt16[nt * 16 + l][seg * 8];
      bf16x8 bv1 = *(const bf16x8*)&Vt16[nt * 16 + l][seg * 8 + 32];
      O[nt] = __builtin_amdgcn_mfma_f32_16x16x32_bf16(ac0, bv0, O[nt], 0, 0, 0);
      O[nt] = __builtin_amdgcn_mfma_f32_16x16x32_bf16(ac1, bv1, O[nt], 0, 0, 0);
    }
  }

  // ---- low-boundary pending resolution (chunk does not reach key 0) ----
  if (lo > 0) {
    const int m = lo << 6;             // chunk's lowest key
    const float mb = imask[n * S_LEN + m - 1];
    // score[row=l] partial over dims seg*16..+15, then reduce across segs
    const __bf16* kb = Kh + (((size_t)nh * S_LEN + m - 1) << 6) + seg * 16;
    bf16x8 kb0 = *(const bf16x8*)kb, kb1 = *(const bf16x8*)(kb + 8);
    bf16x8 q0 = *(const bf16x8*)&Qs16[wv * 16 + l][seg * 16];
    bf16x8 q1 = *(const bf16x8*)&Qs16[wv * 16 + l][seg * 16 + 8];
    float sc_ = 0.f;
#pragma unroll
    for (int j = 0; j < 8; ++j)
      sc_ += (float)q0[j] * (float)kb0[j] + (float)q1[j] * (float)kb1[j];
    sc_ += __shfl_xor(sc_, 16);
    sc_ += __shfl_xor(sc_, 32);        // all lanes of row l now hold full dot
    const float fbl = 1.f - mb * __builtin_amdgcn_rcpf(1.f + __expf(-sc_)) + EPS_G;
#pragma unroll
    for (int reg = 0; reg < 4; ++reg) {
      const float fb = __shfl(fbl, (wv << 6 & 0) + (seg << 2) + reg); // lane l=seg*4+reg
#pragma unroll
      for (int nt = 0; nt < 4; ++nt) O[nt][reg] += pend[reg][nt] * fb;
    }
  }

  if (nc == 1) {
    // direct att write (bf16)
#pragma unroll
    for (int nt = 0; nt < 4; ++nt)
#pragma unroll
      for (int reg = 0; reg < 4; ++reg) {
        const int srow = rb * 64 + wv * 16 + seg * 4 + reg;
        att[((size_t)(n * S_LEN + srow)) * DMODEL + h * HDIM + nt * 16 + l] =
            (__bf16)O[nt][reg];
      }
  } else {
    const int slot = nh * 72 + (t - 8);
    float* po = PartO + (size_t)slot * 4096;
#pragma unroll
    for (int nt = 0; nt < 4; ++nt)
#pragma unroll
      for (int reg = 0; reg < 4; ++reg)
        po[(wv * 16 + seg * 4 + reg) * 64 + nt * 16 + l] = O[nt][reg];
    if (l == 0) {
#pragma unroll
      for (int reg = 0; reg < 4; ++reg)
        PartP[slot * 64 + wv * 16 + seg * 4 + reg] = Crow[reg];
      if (lo == 0) {
#pragma unroll
        for (int reg = 0; reg < 4; ++reg)
          PartA0[(nh * 24 + rb - 8) * 64 + wv * 16 + seg * 4 + reg] = a0k0[reg];
      }
    }
  }
}

// ---------------------------------------------------------------------------
// Kernel 3: combine chunk partials: O = sum_c (prod_{c'<c} P_c') O_c + a0 (x) V0
// One block per (nh, rb>=8).  Writes att bf16.
// ---------------------------------------------------------------------------
__global__ __launch_bounds__(256) void combine_kernel(
    const float* __restrict__ PartO, const float* __restrict__ PartP,
    const float* __restrict__ PartA0, const __bf16* __restrict__ Vt,
    __bf16* __restrict__ att) {
  const int b = blockIdx.x;            // 16 x 24
  const int nh = b / 24;
  const int rb = 8 + (b - nh * 24);
  const int nc = (rb < 16) ? 2 : ((rb < 24) ? 3 : 4);
  const int t0 = (rb < 16) ? 8 + ((rb - 8) << 1)
               : (rb < 24) ? 24 + (rb - 16) * 3
                           : 48 + ((rb - 24) << 2);
  const int n = nh >> 3, h = nh & 7;
  const int tid = threadIdx.x;
  const int r = tid >> 2, db = (tid & 3) << 4;

  float acc[16];
#pragma unroll
  for (int j = 0; j < 16; ++j) acc[j] = 0.f;
  float fac = 1.f;
  for (int c = 0; c < nc; ++c) {
    const int slot = nh * 72 + (t0 - 8) + c;
    const float* po = PartO + (size_t)slot * 4096 + r * 64 + db;
    const float P = PartP[slot * 64 + r];
#pragma unroll
    for (int q = 0; q < 4; ++q) {
      const float4 v = *(const float4*)(po + q * 4);
      acc[q * 4 + 0] += fac * v.x; acc[q * 4 + 1] += fac * v.y;
      acc[q * 4 + 2] += fac * v.z; acc[q * 4 + 3] += fac * v.w;
    }
    fac *= P;
  }
  // t=0 term: coefficient exactly a[0] (no suffix factors)
  const float a0 = PartA0[(nh * 24 + rb - 8) * 64 + r];
#pragma unroll
  for (int j = 0; j < 16; ++j)
    acc[j] += a0 * (float)Vt[(((size_t)(nh * 64 + db + j)) << 11)];

  __bf16 ob[16];
#pragma unroll
  for (int j = 0; j < 16; ++j) ob[j] = (__bf16)acc[j];
  __bf16* dst = att + ((size_t)(n * S_LEN + rb * 64 + r)) * DMODEL + h * HDIM + db;
  *(bf16x8*)dst       = *(bf16x8*)&ob[0];
  *(bf16x8*)(dst + 8) = *(bf16x8*)&ob[8];
}

// ---------------------------------------------------------------------------
// Kernel 4: out = att @ Wo^T + bo.  64x128 tile, att bf16 direct staging,
// register-prefetch double-buffered K-loop.
// ---------------------------------------------------------------------------
__global__ __launch_bounds__(256, 2) void out_gemm(const __bf16* __restrict__ Xa,
                                                   const __bf16* __restrict__ Wob,
                                                   const float* __restrict__ bo,
                                                   float* __restrict__ Out) {
  const int i0 = blockIdx.x << 6, j0 = blockIdx.y << 7;
  __shared__ __bf16 As[64][72];
  __shared__ __bf16 Bs[128][72];

  const int tid = threadIdx.x;
  const int wv = tid >> 6, lane = tid & 63;
  const int l = lane & 15, seg = lane >> 4;
  const int sr = tid >> 2, sc = (tid & 3) << 4;

  f32x4 O[8];
#pragma unroll
  for (int nt = 0; nt < 8; ++nt) O[nt] = (f32x4){0.f, 0.f, 0.f, 0.f};

  bf16x8 ar0, ar1, br[2][2];
#define LOADOUT(K0)                                                          \
  {                                                                          \
    const __bf16* xp = Xa + (size_t)(i0 + sr) * 512 + (K0) + sc;             \
    ar0 = *(const bf16x8*)xp; ar1 = *(const bf16x8*)(xp + 8);                \
    _Pragma("unroll")                                                        \
    for (int ps = 0; ps < 2; ++ps) {                                         \
      const __bf16* wp = Wob + (size_t)(j0 + ps * 64 + sr) * 512 + (K0) + sc;\
      br[ps][0] = *(const bf16x8*)wp; br[ps][1] = *(const bf16x8*)(wp + 8);  \
    }                                                                        \
  }

  LOADOUT(0)
  for (int k0 = 0; k0 < 512; k0 += 64) {
    __syncthreads();
    *(bf16x8*)&As[sr][sc]     = ar0;
    *(bf16x8*)&As[sr][sc + 8] = ar1;
#pragma unroll
    for (int ps = 0; ps < 2; ++ps) {
      *(bf16x8*)&Bs[ps * 64 + sr][sc]     = br[ps][0];
      *(bf16x8*)&Bs[ps * 64 + sr][sc + 8] = br[ps][1];
    }
    __syncthreads();
    if (k0 < 448) LOADOUT(k0 + 64)

    bf16x8 a0 = *(const bf16x8*)&As[wv * 16 + l][seg * 8];
    bf16x8 a1 = *(const bf16x8*)&As[wv * 16 + l][seg * 8 + 32];
#pragma unroll
    for (int nt = 0; nt < 8; ++nt) {
      bf16x8 b0 = *(const bf16x8*)&Bs[nt * 16 + l][seg * 8];
      bf16x8 b1 = *(const bf16x8*)&Bs[nt * 16 + l][seg * 8 + 32];
      O[nt] = __builtin_amdgcn_mfma_f32_16x16x32_bf16(a0, b0, O[nt], 0, 0, 0);
      O[nt] = __builtin_amdgcn_mfma_f32_16x16x32_bf16(a1, b1, O[nt], 0, 0, 0);
    }
  }

#pragma unroll
  for (int nt = 0; nt < 8; ++nt) {
    const float bb = bo[j0 + nt * 16 + l];
#pragma unroll
    for (int reg = 0; reg < 4; ++reg) {
      const int m = wv * 16 + seg * 4 + reg;
      Out[(size_t)(i0 + m) * 512 + j0 + nt * 16 + l] = O[nt][reg] + bb;
    }
  }
}

// ---------------------------------------------------------------------------
extern "C" void kernel_launch(void* const* d_in, const int* in_sizes, int n_in,
                              void* d_out, int out_size, void* d_ws, size_t ws_size,
                              hipStream_t stream) {
  (void)in_sizes; (void)n_in; (void)out_size; (void)ws_size;
  const float* seq  = (const float*)d_in[0];
  const float* mask = (const float*)d_in[1];
  const int*   pos  = (const int*)d_in[2];
  const float* Wq = (const float*)d_in[4];
  const float* bq = (const float*)d_in[5];
  const float* Wk = (const float*)d_in[6];
  const float* bk = (const float*)d_in[7];
  const float* Wv = (const float*)d_in[8];
  const float* bv = (const float*)d_in[9];
  const float* Wo = (const float*)d_in[10];
  const float* bo = (const float*)d_in[11];
  float* out = (float*)d_out;

  char* base = (char*)d_ws;
  __bf16* att = (__bf16*)base;                     // 4 MB  (4096 x 512 bf16)
  __bf16* Qh  = (__bf16*)(base + ( 4u << 20));     // 4 MB
  __bf16* Kh  = (__bf16*)(base + ( 8u << 20));     // 4 MB
  __bf16* Vt  = (__bf16*)(base + (12u << 20));     // 4 MB  [nh][d][2048]
  __bf16* Wb  = (__bf16*)(base + (16u << 20));     // 1.5 MB
  __bf16* Wob = (__bf16*)(base + (18u << 20));     // 0.5 MB
  __bf16* Xb  = (__bf16*)(base + (19u << 20));     // 4 MB  (dead after qkv)
  float* PartO  = (float*)(base + (23u << 20));    // 16*72*4096*4 = 18.9 MB
  float* PartP  = (float*)(base + (42u << 20));    // 16*72*64*4   = 295 KB
  float* PartA0 = (float*)(base + (43u << 20));    // 16*24*64*4   = 98 KB
  // total ~43.2 MB (assumed ws_size >= 44 MB; >=32 MB proven in R1)

  cvt_kernel<<<3072, 256, 0, stream>>>(seq, Wq, Wk, Wv, Wo, Xb, Wb, Wob);
  qkv_gemm<<<dim3(64, 8), 256, 0, stream>>>(Xb, Wb, bq, bk, bv, pos, Qh, Kh, Vt);
  attn_chunk<<<1280, 256, 0, stream>>>(Qh, Kh, Vt, mask, att, PartO, PartP, PartA0);
  combine_kernel<<<384, 256, 0, stream>>>(PartO, PartP, PartA0, Vt, att);
  out_gemm<<<dim3(64, 4), 256, 0, stream>>>(att, Wob, bo, out);
}